// Round 1
// baseline (938.911 us; speedup 1.0000x reference)
//
#include <hip/hip_runtime.h>
#include <stdint.h>

typedef unsigned short u16;
typedef unsigned int   u32;
typedef unsigned long long u64;

typedef __bf16 v8bf __attribute__((ext_vector_type(8)));
typedef float  v4f  __attribute__((ext_vector_type(4)));

// ---- problem constants ----
#define NBATCH 32
#define NCH    512
#define FH     50
#define FW     37
#define PIX    1850        // 50*37
#define MTOT   59200       // 32*1850
#define KTOT   4608        // 512*9
#define HP     52          // padded H
#define WP     39          // padded W
#define NG     20

#define PROB_N 1065600     // 32*18*1850
#define LOC_N  2131200     // 32*36*1850
#define LC_IDX 3196800
#define LL_IDX 3196801

__device__ __forceinline__ u16 f2bf(float f) {          // round-to-nearest-even
    u32 u = __float_as_uint(f);
    u += 0x7fffu + ((u >> 16) & 1u);
    return (u16)(u >> 16);
}
__device__ __forceinline__ float bf_lo(u32 u){ return __uint_as_float(u << 16); }
__device__ __forceinline__ float bf_hi(u32 u){ return __uint_as_float(u & 0xffff0000u); }

// ---------------------------------------------------------------------------
// feats NCHW fp32 -> zero-padded NHWC bf16  [B][52][39][512]
// LDS 64x64 tile transpose; border already zeroed by memset.
// ---------------------------------------------------------------------------
__global__ __launch_bounds__(256) void pad_kernel(const float* __restrict__ feats,
                                                  u16* __restrict__ fpad) {
    __shared__ float t[64][65];
    const int b  = blockIdx.z;
    const int c0 = blockIdx.y * 64;
    const int p0 = blockIdx.x * 64;
    const int tid = threadIdx.x;
    {
        const int cl = tid >> 2, seg = tid & 3;
        const float* src = feats + ((size_t)b * NCH + c0 + cl) * PIX;
        const int pbase = p0 + seg * 16;
        #pragma unroll
        for (int i = 0; i < 16; i++) {
            int p = pbase + i;
            t[cl][seg * 16 + i] = (p < PIX) ? src[p] : 0.f;
        }
    }
    __syncthreads();
    {
        const int pl = tid >> 2, cs = tid & 3;
        const int p = p0 + pl;
        if (p < PIX) {
            const int h = p / FW, w = p % FW;
            size_t dst = (((size_t)b * HP + h + 1) * WP + (w + 1)) * NCH + c0 + cs * 16;
            u32 pk[8];
            #pragma unroll
            for (int i = 0; i < 8; i++) {
                u32 lo = f2bf(t[cs * 16 + 2 * i][pl]);
                u32 hi = f2bf(t[cs * 16 + 2 * i + 1][pl]);
                pk[i] = lo | (hi << 16);
            }
            *(uint4*)&fpad[dst]     = make_uint4(pk[0], pk[1], pk[2], pk[3]);
            *(uint4*)&fpad[dst + 8] = make_uint4(pk[4], pk[5], pk[6], pk[7]);
        }
    }
}

// ---------------------------------------------------------------------------
// W3 [co][ci][3][3] fp32 -> Wbt [co][k] bf16, k = (dy*3+dx)*512 + ci
// ---------------------------------------------------------------------------
__global__ void wprep3(const float* __restrict__ w3, u16* __restrict__ wbt) {
    int t = blockIdx.x * 256 + threadIdx.x;
    if (t < NCH * KTOT) {
        int co = t / KTOT, k = t % KTOT;
        int dydx = k >> 9, ci = k & 511;
        wbt[t] = f2bf(w3[((size_t)co * NCH + ci) * 9 + dydx]);
    }
}

// Wcls [18][512] + Wloc [36][512] fp32 -> Wcb [54][512] bf16
__global__ void wprep1(const float* __restrict__ wcls, const float* __restrict__ wloc,
                       u16* __restrict__ wcb) {
    int t = blockIdx.x * 256 + threadIdx.x;
    if (t < 54 * 512) {
        int c = t >> 9, ci = t & 511;
        float v = (c < 18) ? wcls[c * 512 + ci] : wloc[(c - 18) * 512 + ci];
        wcb[t] = f2bf(v);
    }
}

// ---------------------------------------------------------------------------
// conv3x3 + bias + relu as implicit GEMM, bf16 MFMA 16x16x32
// A[m][k] = fpad[b][y+dy][x+dx][ci], B[k][n] = Wbt[n][k] (stored transposed)
// Tile 128x128, BK=32, 4 waves in 2x2, each wave 64x64 (4x4 MFMA frags)
// ---------------------------------------------------------------------------
__global__ __launch_bounds__(256) void conv3x3_mfma(const u16* __restrict__ fpad,
                                                    const u16* __restrict__ wbt,
                                                    const float* __restrict__ b3,
                                                    u16* __restrict__ conv1) {
    __shared__ __align__(16) u16 As[128][40];   // +8 pad: stride 80B breaks conflicts
    __shared__ __align__(16) u16 Bs[128][40];

    const int tid = threadIdx.x;
    const int m_base = blockIdx.x * 128;
    const int n_base = blockIdx.y * 128;

    const int row = tid >> 2;     // staging row (this thread also does row+64)
    const int seg = tid & 3;      // 8-elem (16B) segment within the 32-wide K slab

    int rb[2];                    // per-row base offset into fpad (elements)
    #pragma unroll
    for (int r = 0; r < 2; r++) {
        int m = m_base + row + r * 64;
        int mm = (m < MTOT) ? m : 0;
        int b = mm / PIX;
        int p = mm % PIX;
        int y = p / FW;
        int x = p % FW;
        rb[r] = ((b * HP + y) * WP + x) * NCH;   // (y,x) in pad coords == dy=dx=0
    }
    int wbrow[2];
    #pragma unroll
    for (int r = 0; r < 2; r++) {
        int n = n_base + row + r * 64;
        wbrow[r] = n * KTOT + seg * 8;
    }

    const int lane = tid & 63;
    const int wave = tid >> 6;
    const int wm = (wave >> 1) * 64;
    const int wn = (wave & 1) * 64;
    const int lm = lane & 15;
    const int quad = lane >> 4;
    const int q8 = quad * 8;

    v4f acc[4][4];
    #pragma unroll
    for (int i = 0; i < 4; i++)
        #pragma unroll
        for (int j = 0; j < 4; j++)
            #pragma unroll
            for (int r = 0; r < 4; r++) acc[i][j][r] = 0.f;

    for (int k0 = 0; k0 < KTOT; k0 += 32) {
        const int dydx = k0 >> 9;
        const int ci0  = k0 & 511;
        const int offA = ((dydx / 3) * WP + (dydx % 3)) * NCH + ci0 + seg * 8;
        #pragma unroll
        for (int r = 0; r < 2; r++)
            *(uint4*)&As[row + r * 64][seg * 8] = *(const uint4*)&fpad[rb[r] + offA];
        #pragma unroll
        for (int r = 0; r < 2; r++)
            *(uint4*)&Bs[row + r * 64][seg * 8] = *(const uint4*)&wbt[wbrow[r] + k0];
        __syncthreads();

        v8bf af[4], bfv[4];
        #pragma unroll
        for (int i = 0; i < 4; i++) af[i]  = *(const v8bf*)&As[wm + i * 16 + lm][q8];
        #pragma unroll
        for (int i = 0; i < 4; i++) bfv[i] = *(const v8bf*)&Bs[wn + i * 16 + lm][q8];
        #pragma unroll
        for (int i = 0; i < 4; i++)
            #pragma unroll
            for (int j = 0; j < 4; j++)
                acc[i][j] = __builtin_amdgcn_mfma_f32_16x16x32_bf16(af[i], bfv[j], acc[i][j], 0, 0, 0);
        __syncthreads();
    }

    // epilogue: bias + relu, store bf16 conv1[m][n]
    #pragma unroll
    for (int j = 0; j < 4; j++) {
        const int n = n_base + wn + j * 16 + lm;
        const float bias = b3[n];
        #pragma unroll
        for (int i = 0; i < 4; i++) {
            #pragma unroll
            for (int r = 0; r < 4; r++) {
                int m = m_base + wm + i * 16 + quad * 4 + r;
                if (m < MTOT) {
                    float v = acc[i][j][r] + bias;
                    v = v > 0.f ? v : 0.f;
                    conv1[(size_t)m * NCH + n] = f2bf(v);
                }
            }
        }
    }
}

// ---------------------------------------------------------------------------
// head: cls (18) + loc (36) 1x1 convs over conv1, fused pairwise softmax.
// Block = 4 pixels x 64 channel-slots (54 used). tid: c = tid>>2, pix = tid&3
// ---------------------------------------------------------------------------
__global__ __launch_bounds__(256) void head_kernel(const u16* __restrict__ conv1,
                                                   const u16* __restrict__ wcb,
                                                   const float* __restrict__ bcls,
                                                   const float* __restrict__ bloc,
                                                   float* __restrict__ out) {
    __shared__ __align__(16) u16 xl[4][520];
    __shared__ float cls_l[4][18];
    const int tid = threadIdx.x;
    const int m0 = blockIdx.x * 4;
    {
        const int r = tid & 3;
        const int kk = (tid >> 2) * 8;
        *(uint4*)&xl[r][kk] = *(const uint4*)&conv1[(size_t)(m0 + r) * NCH + kk];
    }
    __syncthreads();
    const int c = tid >> 2;
    const int pix = tid & 3;
    float acc = 0.f;
    if (c < 54) {
        const uint4* wp = (const uint4*)(wcb + c * 512);
        #pragma unroll 8
        for (int it = 0; it < 64; it++) {
            uint4 xv = *(const uint4*)&xl[pix][it * 8];
            uint4 wv = wp[it];
            acc = fmaf(bf_lo(xv.x), bf_lo(wv.x), acc);
            acc = fmaf(bf_hi(xv.x), bf_hi(wv.x), acc);
            acc = fmaf(bf_lo(xv.y), bf_lo(wv.y), acc);
            acc = fmaf(bf_hi(xv.y), bf_hi(wv.y), acc);
            acc = fmaf(bf_lo(xv.z), bf_lo(wv.z), acc);
            acc = fmaf(bf_hi(xv.z), bf_hi(wv.z), acc);
            acc = fmaf(bf_lo(xv.w), bf_lo(wv.w), acc);
            acc = fmaf(bf_hi(xv.w), bf_hi(wv.w), acc);
        }
    }
    const int m = m0 + pix;
    const int b = m / PIX;
    const int p = m % PIX;
    if (c >= 18 && c < 54) {
        out[(size_t)PROB_N + ((size_t)b * 36 + (c - 18)) * PIX + p] = acc + bloc[c - 18];
    }
    if (c < 18) cls_l[pix][c] = acc + bcls[c];
    __syncthreads();
    if (c < 9) {
        float s0 = cls_l[pix][c], s1 = cls_l[pix][c + 9];
        float mx = fmaxf(s0, s1);
        float e0 = expf(s0 - mx), e1 = expf(s1 - mx);
        float inv = 1.f / (e0 + e1);
        out[((size_t)b * 18 + c) * PIX + p]     = e0 * inv;
        out[((size_t)b * 18 + c + 9) * PIX + p] = e1 * inv;
    }
}

// ---------------------------------------------------------------------------
// per-(b,a): max IoU over 20 GTs + argmax (first-max); per-(b,g) best anchor
// via u64 key (iou_bits<<32 | ~a) -> first-index tie-break, wave-reduced.
// ---------------------------------------------------------------------------
__global__ __launch_bounds__(256) void iou_kernel(const float* __restrict__ anchors,
                                                  const float* __restrict__ gtb,
                                                  int A,
                                                  float* __restrict__ max_iou,
                                                  int* __restrict__ matched,
                                                  u64* __restrict__ gtkey) {
    __shared__ float g[NG * 4];
    __shared__ u64 wk[4][NG];
    const int b = blockIdx.y;
    const int tid = threadIdx.x;
    if (tid < NG * 4) g[tid] = gtb[b * NG * 4 + tid];
    __syncthreads();
    const int a = blockIdx.x * 256 + tid;
    const bool act = a < A;
    const int aa = act ? a : 0;
    const float ax1 = anchors[aa * 4 + 0], ay1 = anchors[aa * 4 + 1];
    const float ax2 = anchors[aa * 4 + 2], ay2 = anchors[aa * 4 + 3];
    const float areaA = (ax2 - ax1) * (ay2 - ay1);
    float best = -1.f;
    int bg = 0;
    const int lane = tid & 63, wave = tid >> 6;
    for (int gi = 0; gi < NG; gi++) {
        float gx1 = g[gi * 4], gy1 = g[gi * 4 + 1], gx2 = g[gi * 4 + 2], gy2 = g[gi * 4 + 3];
        float iw = fmaxf(fminf(ax2, gx2) - fmaxf(ax1, gx1), 0.f);
        float ih = fmaxf(fminf(ay2, gy2) - fmaxf(ay1, gy1), 0.f);
        float inter = iw * ih;
        float areaG = (gx2 - gx1) * (gy2 - gy1);
        float iou = inter / fmaxf(areaA + areaG - inter, 1e-8f);
        if (act && iou > best) { best = iou; bg = gi; }
        u64 key = act ? (((u64)__float_as_uint(iou) << 32) | (u64)(0xFFFFFFFFu - (u32)a)) : 0ull;
        #pragma unroll
        for (int off = 32; off; off >>= 1) {
            u64 o = __shfl_xor(key, off);
            key = (o > key) ? o : key;
        }
        if (lane == 0) wk[wave][gi] = key;
    }
    if (act) {
        max_iou[(size_t)b * A + a] = best;
        matched[(size_t)b * A + a] = bg;
    }
    __syncthreads();
    if (tid < NG) {
        u64 k = wk[0][tid];
        k = (wk[1][tid] > k) ? wk[1][tid] : k;
        k = (wk[2][tid] > k) ? wk[2][tid] : k;
        k = (wk[3][tid] > k) ? wk[3][tid] : k;
        atomicMax(&gtkey[b * NG + tid], k);
    }
}

// ---------------------------------------------------------------------------
// losses: labels = (best-anchor-of-some-gt) | (max_iou > 0.7)
// loss_cls = mean(-log p_label);  loss_loc = sum(smoothL1)*label / 256
// ---------------------------------------------------------------------------
__global__ __launch_bounds__(256) void loss_kernel(const float* __restrict__ gtb,
                                                   const int* __restrict__ idxs,
                                                   const float* __restrict__ max_iou,
                                                   const int* __restrict__ matched,
                                                   const u64* __restrict__ gtkey,
                                                   int A,
                                                   float* out) {
    __shared__ float g[NG * 4];
    __shared__ int gbest[NG];
    __shared__ float red[8];
    const int b = blockIdx.y;
    const int tid = threadIdx.x;
    if (tid < NG * 4) g[tid] = gtb[b * NG * 4 + tid];
    if (tid < NG) {
        u64 k = gtkey[b * NG + tid];
        gbest[tid] = (int)(0xFFFFFFFFu - (u32)(k & 0xFFFFFFFFull));
    }
    __syncthreads();
    const int a = blockIdx.x * 256 + tid;
    float lc = 0.f, ll = 0.f;
    if (a < A) {
        float mi = max_iou[(size_t)b * A + a];
        int lbl = (mi > 0.7f) ? 1 : 0;
        if (!lbl) {
            #pragma unroll
            for (int gi = 0; gi < NG; gi++) lbl |= (gbest[gi] == a);
        }
        const int idx = idxs[a];
        // cls ordering: idx = c'*1850 + h*37 + w  (channel-major)
        const int cpr = idx / PIX;
        const int rem = idx % PIX;
        float p0 = out[((size_t)b * 18 + cpr) * PIX + rem];
        float p1 = out[((size_t)b * 18 + cpr + 9) * PIX + rem];
        float pl = lbl ? p1 : p0;
        lc = -logf(pl);
        if (lbl) {
            const int mg = matched[(size_t)b * A + a];
            // loc ordering: idx = h*333 + w*9 + c4   (spatial-major)
            const int hh = idx / 333;
            const int r2 = idx % 333;
            const int ww = r2 / 9;
            const int c4 = r2 % 9;
            const int pp = hh * FW + ww;
            #pragma unroll
            for (int t = 0; t < 4; t++) {
                float lv = out[(size_t)PROB_N + ((size_t)b * 36 + c4 * 4 + t) * PIX + pp];
                float d = lv - g[mg * 4 + t];
                float ad = fabsf(d);
                ll += (ad < 1.f) ? 0.5f * d * d : ad - 0.5f;
            }
        }
    }
    #pragma unroll
    for (int off = 32; off; off >>= 1) {
        lc += __shfl_xor(lc, off);
        ll += __shfl_xor(ll, off);
    }
    const int lane = tid & 63, wave = tid >> 6;
    if (lane == 0) { red[wave] = lc; red[4 + wave] = ll; }
    __syncthreads();
    if (tid == 0) {
        float slc = red[0] + red[1] + red[2] + red[3];
        float sll = red[4] + red[5] + red[6] + red[7];
        atomicAdd(&out[LC_IDX], slc * (1.f / (32.f * (float)A)));
        atomicAdd(&out[LL_IDX], sll * (1.f / 256.f));
    }
}

// ---------------------------------------------------------------------------
extern "C" void kernel_launch(void* const* d_in, const int* in_sizes, int n_in,
                              void* d_out, int out_size, void* d_ws, size_t ws_size,
                              hipStream_t stream) {
    const float* feats   = (const float*)d_in[0];
    const float* gtb     = (const float*)d_in[1];
    const float* anchors = (const float*)d_in[2];
    const float* W3      = (const float*)d_in[3];
    const float* b3      = (const float*)d_in[4];
    const float* Wcls    = (const float*)d_in[5];
    const float* bcls    = (const float*)d_in[6];
    const float* Wloc    = (const float*)d_in[7];
    const float* bloc    = (const float*)d_in[8];
    const int*   idxs    = (const int*)d_in[9];
    const int A = in_sizes[9];
    float* out = (float*)d_out;

    char* ws = (char*)d_ws;
    size_t off = 0;
    auto alloc = [&](size_t bytes) -> void* {
        void* p = ws + off;
        off = (off + bytes + 255) & ~(size_t)255;
        return p;
    };
    const size_t fpad_n = (size_t)NBATCH * HP * WP * NCH;     // 33,226,752
    u16* fpad   = (u16*)alloc(fpad_n * 2);
    u16* wbt    = (u16*)alloc((size_t)NCH * KTOT * 2);
    u16* wcb    = (u16*)alloc((size_t)54 * 512 * 2);
    u16* conv1  = (u16*)alloc((size_t)MTOT * NCH * 2);
    u64* gtkey  = (u64*)alloc((size_t)NBATCH * NG * 8);
    float* max_iou = (float*)alloc((size_t)NBATCH * A * 4);
    int*   matched = (int*)alloc((size_t)NBATCH * A * 4);

    hipMemsetAsync(fpad, 0, fpad_n * 2, stream);
    hipMemsetAsync(gtkey, 0, (size_t)NBATCH * NG * 8, stream);
    hipMemsetAsync(out + LC_IDX, 0, 8, stream);

    pad_kernel<<<dim3(29, 8, NBATCH), 256, 0, stream>>>(feats, fpad);
    wprep3<<<(NCH * KTOT + 255) / 256, 256, 0, stream>>>(W3, wbt);
    wprep1<<<(54 * 512 + 255) / 256, 256, 0, stream>>>(Wcls, Wloc, wcb);
    conv3x3_mfma<<<dim3(463, 4), 256, 0, stream>>>(fpad, wbt, b3, conv1);
    head_kernel<<<MTOT / 4, 256, 0, stream>>>(conv1, wcb, bcls, bloc, out);
    const int ablk = (A + 255) / 256;
    iou_kernel<<<dim3(ablk, NBATCH), 256, 0, stream>>>(anchors, gtb, A, max_iou, matched, gtkey);
    loss_kernel<<<dim3(ablk, NBATCH), 256, 0, stream>>>(gtb, idxs, max_iou, matched, gtkey, A, out);
}

// Round 2
// 912.899 us; speedup vs baseline: 1.0285x; 1.0285x over previous
//
#include <hip/hip_runtime.h>
#include <stdint.h>

typedef unsigned short u16;
typedef unsigned int   u32;
typedef unsigned long long u64;

typedef __bf16 v8bf __attribute__((ext_vector_type(8)));
typedef float  v4f  __attribute__((ext_vector_type(4)));

// ---- problem constants ----
#define NBATCH 32
#define NCH    512
#define FH     50
#define FW     37
#define PIX    1850        // 50*37
#define MTOT   59200       // 32*1850
#define KTOT   4608        // 512*9
#define HP     52          // padded H
#define WP     39          // padded W
#define NG     20

#define PROB_N 1065600     // 32*18*1850
#define LOC_N  2131200     // 32*36*1850
#define LC_IDX 3196800
#define LL_IDX 3196801

__device__ __forceinline__ u16 f2bf(float f) {          // round-to-nearest-even
    u32 u = __float_as_uint(f);
    u += 0x7fffu + ((u >> 16) & 1u);
    return (u16)(u >> 16);
}
__device__ __forceinline__ float bf_lo(u32 u){ return __uint_as_float(u << 16); }
__device__ __forceinline__ float bf_hi(u32 u){ return __uint_as_float(u & 0xffff0000u); }

// async global->LDS, 16B per lane. LDS dst = wave-uniform base + lane*16 (m104).
__device__ __forceinline__ void gl_lds16(const u16* g, u16* l) {
    __builtin_amdgcn_global_load_lds((const __attribute__((address_space(1))) u32*)g,
                                     (__attribute__((address_space(3))) u32*)l,
                                     16, 0, 0);
}

// ---------------------------------------------------------------------------
// feats NCHW fp32 -> zero-padded NHWC bf16  [B][52][39][512]
// ---------------------------------------------------------------------------
__global__ __launch_bounds__(256) void pad_kernel(const float* __restrict__ feats,
                                                  u16* __restrict__ fpad) {
    __shared__ float t[64][65];
    const int b  = blockIdx.z;
    const int c0 = blockIdx.y * 64;
    const int p0 = blockIdx.x * 64;
    const int tid = threadIdx.x;
    {
        const int cl = tid >> 2, seg = tid & 3;
        const float* src = feats + ((size_t)b * NCH + c0 + cl) * PIX;
        const int pbase = p0 + seg * 16;
        #pragma unroll
        for (int i = 0; i < 16; i++) {
            int p = pbase + i;
            t[cl][seg * 16 + i] = (p < PIX) ? src[p] : 0.f;
        }
    }
    __syncthreads();
    {
        const int pl = tid >> 2, cs = tid & 3;
        const int p = p0 + pl;
        if (p < PIX) {
            const int h = p / FW, w = p % FW;
            size_t dst = (((size_t)b * HP + h + 1) * WP + (w + 1)) * NCH + c0 + cs * 16;
            u32 pk[8];
            #pragma unroll
            for (int i = 0; i < 8; i++) {
                u32 lo = f2bf(t[cs * 16 + 2 * i][pl]);
                u32 hi = f2bf(t[cs * 16 + 2 * i + 1][pl]);
                pk[i] = lo | (hi << 16);
            }
            *(uint4*)&fpad[dst]     = make_uint4(pk[0], pk[1], pk[2], pk[3]);
            *(uint4*)&fpad[dst + 8] = make_uint4(pk[4], pk[5], pk[6], pk[7]);
        }
    }
}

// ---------------------------------------------------------------------------
// W3 [co][ci][3][3] fp32 -> Wbt [co][k] bf16, k = (dy*3+dx)*512 + ci
// ---------------------------------------------------------------------------
__global__ void wprep3(const float* __restrict__ w3, u16* __restrict__ wbt) {
    int t = blockIdx.x * 256 + threadIdx.x;
    if (t < NCH * KTOT) {
        int co = t / KTOT, k = t % KTOT;
        int dydx = k >> 9, ci = k & 511;
        wbt[t] = f2bf(w3[((size_t)co * NCH + ci) * 9 + dydx]);
    }
}

// Wcls [18][512] + Wloc [36][512] fp32 -> Wcb [54][512] bf16
__global__ void wprep1(const float* __restrict__ wcls, const float* __restrict__ wloc,
                       u16* __restrict__ wcb) {
    int t = blockIdx.x * 256 + threadIdx.x;
    if (t < 54 * 512) {
        int c = t >> 9, ci = t & 511;
        float v = (c < 18) ? wcls[c * 512 + ci] : wloc[(c - 18) * 512 + ci];
        wcb[t] = f2bf(v);
    }
}

// ---------------------------------------------------------------------------
// conv3x3 + bias + relu as implicit GEMM, bf16 MFMA 16x16x32, m97 structure:
// global_load_lds width=16 staging into UNPADDED [128][32] tiles (the
// wave-uniform-base + lane*16 scatter forbids padding). Staging map:
// slot = r*256 + tid -> row = r*64 + (tid>>2), kseg = tid&3 == lane order.
// ---------------------------------------------------------------------------
__global__ __launch_bounds__(256) void conv3x3_mfma(const u16* __restrict__ fpad,
                                                    const u16* __restrict__ wbt,
                                                    const float* __restrict__ b3,
                                                    u16* __restrict__ conv1) {
    __shared__ __align__(16) u16 As[128][32];
    __shared__ __align__(16) u16 Bs[128][32];

    const int tid = threadIdx.x;
    const int m_base = blockIdx.x * 128;
    const int n_base = blockIdx.y * 128;

    const int row = tid >> 2;     // staging row within a 64-row round
    const int seg = tid & 3;      // 16B segment within the 32-wide K slab
    const int wave = tid >> 6;
    const int lane = tid & 63;

    int rb[2];                    // per-round fpad base offset (elements)
    #pragma unroll
    for (int r = 0; r < 2; r++) {
        int m = m_base + row + r * 64;
        int mm = (m < MTOT) ? m : 0;
        int b = mm / PIX;
        int p = mm % PIX;
        int y = p / FW;
        int x = p % FW;
        rb[r] = ((b * HP + y) * WP + x) * NCH;
    }
    int wbrow[2];
    #pragma unroll
    for (int r = 0; r < 2; r++) {
        int n = n_base + row + r * 64;
        wbrow[r] = n * KTOT + seg * 8;
    }

    // wave-uniform LDS bases: round r, wave w -> byte offset r*4096 + w*1024
    u16* const as0 = &As[0][0] + wave * 512;
    u16* const as1 = &As[0][0] + 2048 + wave * 512;
    u16* const bs0 = &Bs[0][0] + wave * 512;
    u16* const bs1 = &Bs[0][0] + 2048 + wave * 512;

    const int wm = (wave >> 1) * 64;
    const int wn = (wave & 1) * 64;
    const int lm = lane & 15;
    const int quad = lane >> 4;
    const int q8 = quad * 8;

    v4f acc[4][4];
    #pragma unroll
    for (int i = 0; i < 4; i++)
        #pragma unroll
        for (int j = 0; j < 4; j++)
            #pragma unroll
            for (int r = 0; r < 4; r++) acc[i][j][r] = 0.f;

    for (int k0 = 0; k0 < KTOT; k0 += 32) {
        const int dydx = k0 >> 9;
        const int ci0  = k0 & 511;
        const int offA = ((dydx / 3) * WP + (dydx % 3)) * NCH + ci0 + seg * 8;
        gl_lds16(fpad + rb[0] + offA, as0);
        gl_lds16(fpad + rb[1] + offA, as1);
        gl_lds16(wbt + wbrow[0] + k0, bs0);
        gl_lds16(wbt + wbrow[1] + k0, bs1);
        __syncthreads();

        v8bf af[4], bfv[4];
        #pragma unroll
        for (int i = 0; i < 4; i++) af[i]  = *(const v8bf*)&As[wm + i * 16 + lm][q8];
        #pragma unroll
        for (int i = 0; i < 4; i++) bfv[i] = *(const v8bf*)&Bs[wn + i * 16 + lm][q8];
        #pragma unroll
        for (int i = 0; i < 4; i++)
            #pragma unroll
            for (int j = 0; j < 4; j++)
                acc[i][j] = __builtin_amdgcn_mfma_f32_16x16x32_bf16(af[i], bfv[j], acc[i][j], 0, 0, 0);
        __syncthreads();
    }

    // epilogue: bias + relu, store bf16 conv1[m][n]
    #pragma unroll
    for (int j = 0; j < 4; j++) {
        const int n = n_base + wn + j * 16 + lm;
        const float bias = b3[n];
        #pragma unroll
        for (int i = 0; i < 4; i++) {
            #pragma unroll
            for (int r = 0; r < 4; r++) {
                int m = m_base + wm + i * 16 + quad * 4 + r;
                if (m < MTOT) {
                    float v = acc[i][j][r] + bias;
                    v = v > 0.f ? v : 0.f;
                    conv1[(size_t)m * NCH + n] = f2bf(v);
                }
            }
        }
    }
}

// ---------------------------------------------------------------------------
// head: cls (18) + loc (36) 1x1 convs over conv1, fused pairwise softmax.
// Block = 4 pixels x 64 channel-slots. 4 rotating accumulators break the
// fmaf dependency chain (4-cyc latency x 512-deep chain was the limiter).
// ---------------------------------------------------------------------------
__global__ __launch_bounds__(256) void head_kernel(const u16* __restrict__ conv1,
                                                   const u16* __restrict__ wcb,
                                                   const float* __restrict__ bcls,
                                                   const float* __restrict__ bloc,
                                                   float* __restrict__ out) {
    __shared__ __align__(16) u16 xl[4][520];
    __shared__ float cls_l[4][18];
    const int tid = threadIdx.x;
    const int m0 = blockIdx.x * 4;
    {
        const int r = tid & 3;
        const int kk = (tid >> 2) * 8;
        *(uint4*)&xl[r][kk] = *(const uint4*)&conv1[(size_t)(m0 + r) * NCH + kk];
    }
    __syncthreads();
    const int c = tid >> 2;
    const int pix = tid & 3;
    float a0 = 0.f, a1 = 0.f, a2 = 0.f, a3 = 0.f;
    if (c < 54) {
        const uint4* wp = (const uint4*)(wcb + c * 512);
        #pragma unroll 8
        for (int it = 0; it < 64; it++) {
            uint4 xv = *(const uint4*)&xl[pix][it * 8];
            uint4 wv = wp[it];
            a0 = fmaf(bf_lo(xv.x), bf_lo(wv.x), a0);
            a1 = fmaf(bf_hi(xv.x), bf_hi(wv.x), a1);
            a2 = fmaf(bf_lo(xv.y), bf_lo(wv.y), a2);
            a3 = fmaf(bf_hi(xv.y), bf_hi(wv.y), a3);
            a0 = fmaf(bf_lo(xv.z), bf_lo(wv.z), a0);
            a1 = fmaf(bf_hi(xv.z), bf_hi(wv.z), a1);
            a2 = fmaf(bf_lo(xv.w), bf_lo(wv.w), a2);
            a3 = fmaf(bf_hi(xv.w), bf_hi(wv.w), a3);
        }
    }
    float acc = (a0 + a1) + (a2 + a3);
    const int m = m0 + pix;
    const int b = m / PIX;
    const int p = m % PIX;
    if (c >= 18 && c < 54) {
        out[(size_t)PROB_N + ((size_t)b * 36 + (c - 18)) * PIX + p] = acc + bloc[c - 18];
    }
    if (c < 18) cls_l[pix][c] = acc + bcls[c];
    __syncthreads();
    if (c < 9) {
        float s0 = cls_l[pix][c], s1 = cls_l[pix][c + 9];
        float mx = fmaxf(s0, s1);
        float e0 = expf(s0 - mx), e1 = expf(s1 - mx);
        float inv = 1.f / (e0 + e1);
        out[((size_t)b * 18 + c) * PIX + p]     = e0 * inv;
        out[((size_t)b * 18 + c + 9) * PIX + p] = e1 * inv;
    }
}

// ---------------------------------------------------------------------------
// per-(b,a): max IoU over 20 GTs + argmax (first-max); per-(b,g) best anchor
// via u64 key (iou_bits<<32 | ~a) -> first-index tie-break, wave-reduced.
// ---------------------------------------------------------------------------
__global__ __launch_bounds__(256) void iou_kernel(const float* __restrict__ anchors,
                                                  const float* __restrict__ gtb,
                                                  int A,
                                                  float* __restrict__ max_iou,
                                                  int* __restrict__ matched,
                                                  u64* __restrict__ gtkey) {
    __shared__ float g[NG * 4];
    __shared__ u64 wk[4][NG];
    const int b = blockIdx.y;
    const int tid = threadIdx.x;
    if (tid < NG * 4) g[tid] = gtb[b * NG * 4 + tid];
    __syncthreads();
    const int a = blockIdx.x * 256 + tid;
    const bool act = a < A;
    const int aa = act ? a : 0;
    const float ax1 = anchors[aa * 4 + 0], ay1 = anchors[aa * 4 + 1];
    const float ax2 = anchors[aa * 4 + 2], ay2 = anchors[aa * 4 + 3];
    const float areaA = (ax2 - ax1) * (ay2 - ay1);
    float best = -1.f;
    int bg = 0;
    const int lane = tid & 63, wave = tid >> 6;
    for (int gi = 0; gi < NG; gi++) {
        float gx1 = g[gi * 4], gy1 = g[gi * 4 + 1], gx2 = g[gi * 4 + 2], gy2 = g[gi * 4 + 3];
        float iw = fmaxf(fminf(ax2, gx2) - fmaxf(ax1, gx1), 0.f);
        float ih = fmaxf(fminf(ay2, gy2) - fmaxf(ay1, gy1), 0.f);
        float inter = iw * ih;
        float areaG = (gx2 - gx1) * (gy2 - gy1);
        float iou = inter / fmaxf(areaA + areaG - inter, 1e-8f);
        if (act && iou > best) { best = iou; bg = gi; }
        u64 key = act ? (((u64)__float_as_uint(iou) << 32) | (u64)(0xFFFFFFFFu - (u32)a)) : 0ull;
        #pragma unroll
        for (int off = 32; off; off >>= 1) {
            u64 o = __shfl_xor(key, off);
            key = (o > key) ? o : key;
        }
        if (lane == 0) wk[wave][gi] = key;
    }
    if (act) {
        max_iou[(size_t)b * A + a] = best;
        matched[(size_t)b * A + a] = bg;
    }
    __syncthreads();
    if (tid < NG) {
        u64 k = wk[0][tid];
        k = (wk[1][tid] > k) ? wk[1][tid] : k;
        k = (wk[2][tid] > k) ? wk[2][tid] : k;
        k = (wk[3][tid] > k) ? wk[3][tid] : k;
        atomicMax(&gtkey[b * NG + tid], k);
    }
}

// ---------------------------------------------------------------------------
// losses: labels = (best-anchor-of-some-gt) | (max_iou > 0.7)
// loss_cls = mean(-log p_label);  loss_loc = sum(smoothL1)*label / 256
// ---------------------------------------------------------------------------
__global__ __launch_bounds__(256) void loss_kernel(const float* __restrict__ gtb,
                                                   const int* __restrict__ idxs,
                                                   const float* __restrict__ max_iou,
                                                   const int* __restrict__ matched,
                                                   const u64* __restrict__ gtkey,
                                                   int A,
                                                   float* out) {
    __shared__ float g[NG * 4];
    __shared__ int gbest[NG];
    __shared__ float red[8];
    const int b = blockIdx.y;
    const int tid = threadIdx.x;
    if (tid < NG * 4) g[tid] = gtb[b * NG * 4 + tid];
    if (tid < NG) {
        u64 k = gtkey[b * NG + tid];
        gbest[tid] = (int)(0xFFFFFFFFu - (u32)(k & 0xFFFFFFFFull));
    }
    __syncthreads();
    const int a = blockIdx.x * 256 + tid;
    float lc = 0.f, ll = 0.f;
    if (a < A) {
        float mi = max_iou[(size_t)b * A + a];
        int lbl = (mi > 0.7f) ? 1 : 0;
        if (!lbl) {
            #pragma unroll
            for (int gi = 0; gi < NG; gi++) lbl |= (gbest[gi] == a);
        }
        const int idx = idxs[a];
        const int cpr = idx / PIX;
        const int rem = idx % PIX;
        float p0 = out[((size_t)b * 18 + cpr) * PIX + rem];
        float p1 = out[((size_t)b * 18 + cpr + 9) * PIX + rem];
        float pl = lbl ? p1 : p0;
        lc = -logf(pl);
        if (lbl) {
            const int mg = matched[(size_t)b * A + a];
            const int hh = idx / 333;
            const int r2 = idx % 333;
            const int ww = r2 / 9;
            const int c4 = r2 % 9;
            const int pp = hh * FW + ww;
            #pragma unroll
            for (int t = 0; t < 4; t++) {
                float lv = out[(size_t)PROB_N + ((size_t)b * 36 + c4 * 4 + t) * PIX + pp];
                float d = lv - g[mg * 4 + t];
                float ad = fabsf(d);
                ll += (ad < 1.f) ? 0.5f * d * d : ad - 0.5f;
            }
        }
    }
    #pragma unroll
    for (int off = 32; off; off >>= 1) {
        lc += __shfl_xor(lc, off);
        ll += __shfl_xor(ll, off);
    }
    const int lane = tid & 63, wave = tid >> 6;
    if (lane == 0) { red[wave] = lc; red[4 + wave] = ll; }
    __syncthreads();
    if (tid == 0) {
        float slc = red[0] + red[1] + red[2] + red[3];
        float sll = red[4] + red[5] + red[6] + red[7];
        atomicAdd(&out[LC_IDX], slc * (1.f / (32.f * (float)A)));
        atomicAdd(&out[LL_IDX], sll * (1.f / 256.f));
    }
}

// ---------------------------------------------------------------------------
extern "C" void kernel_launch(void* const* d_in, const int* in_sizes, int n_in,
                              void* d_out, int out_size, void* d_ws, size_t ws_size,
                              hipStream_t stream) {
    const float* feats   = (const float*)d_in[0];
    const float* gtb     = (const float*)d_in[1];
    const float* anchors = (const float*)d_in[2];
    const float* W3      = (const float*)d_in[3];
    const float* b3      = (const float*)d_in[4];
    const float* Wcls    = (const float*)d_in[5];
    const float* bcls    = (const float*)d_in[6];
    const float* Wloc    = (const float*)d_in[7];
    const float* bloc    = (const float*)d_in[8];
    const int*   idxs    = (const int*)d_in[9];
    const int A = in_sizes[9];
    float* out = (float*)d_out;

    char* ws = (char*)d_ws;
    size_t off = 0;
    auto alloc = [&](size_t bytes) -> void* {
        void* p = ws + off;
        off = (off + bytes + 255) & ~(size_t)255;
        return p;
    };
    const size_t fpad_n = (size_t)NBATCH * HP * WP * NCH;     // 33,226,752
    u16* fpad   = (u16*)alloc(fpad_n * 2);
    u16* wbt    = (u16*)alloc((size_t)NCH * KTOT * 2);
    u16* wcb    = (u16*)alloc((size_t)54 * 512 * 2);
    u16* conv1  = (u16*)alloc((size_t)MTOT * NCH * 2);
    u64* gtkey  = (u64*)alloc((size_t)NBATCH * NG * 8);
    float* max_iou = (float*)alloc((size_t)NBATCH * A * 4);
    int*   matched = (int*)alloc((size_t)NBATCH * A * 4);

    hipMemsetAsync(fpad, 0, fpad_n * 2, stream);
    hipMemsetAsync(gtkey, 0, (size_t)NBATCH * NG * 8, stream);
    hipMemsetAsync(out + LC_IDX, 0, 8, stream);

    pad_kernel<<<dim3(29, 8, NBATCH), 256, 0, stream>>>(feats, fpad);
    wprep3<<<(NCH * KTOT + 255) / 256, 256, 0, stream>>>(W3, wbt);
    wprep1<<<(54 * 512 + 255) / 256, 256, 0, stream>>>(Wcls, Wloc, wcb);
    conv3x3_mfma<<<dim3(463, 4), 256, 0, stream>>>(fpad, wbt, b3, conv1);
    head_kernel<<<MTOT / 4, 256, 0, stream>>>(conv1, wcb, bcls, bloc, out);
    const int ablk = (A + 255) / 256;
    iou_kernel<<<dim3(ablk, NBATCH), 256, 0, stream>>>(anchors, gtb, A, max_iou, matched, gtkey);
    loss_kernel<<<dim3(ablk, NBATCH), 256, 0, stream>>>(gtb, idxs, max_iou, matched, gtkey, A, out);
}

// Round 3
// 886.291 us; speedup vs baseline: 1.0594x; 1.0300x over previous
//
#include <hip/hip_runtime.h>
#include <stdint.h>

typedef unsigned short u16;
typedef unsigned int   u32;
typedef unsigned long long u64;

typedef __bf16 v8bf __attribute__((ext_vector_type(8)));
typedef float  v4f  __attribute__((ext_vector_type(4)));

// ---- problem constants ----
#define NBATCH 32
#define NCH    512
#define FH     50
#define FW     37
#define PIX    1850        // 50*37
#define MTOT   59200       // 32*1850
#define KTOT   4608        // 512*9
#define HP     52          // padded H
#define WP     39          // padded W
#define NG     20
#define W3N    (NCH*KTOT)  // 2359296

#define PROB_N 1065600     // 32*18*1850
#define LOC_N  2131200     // 32*36*1850
#define LC_IDX 3196800
#define LL_IDX 3196801

__device__ __forceinline__ u16 f2bf(float f) {          // round-to-nearest-even
    u32 u = __float_as_uint(f);
    u += 0x7fffu + ((u >> 16) & 1u);
    return (u16)(u >> 16);
}
__device__ __forceinline__ float bf_lo(u32 u){ return __uint_as_float(u << 16); }
__device__ __forceinline__ float bf_hi(u32 u){ return __uint_as_float(u & 0xffff0000u); }

// async global->LDS, 16B per lane. LDS dst = wave-uniform base + lane*16 (m104).
__device__ __forceinline__ void gl_lds16(const u16* g, u16* l) {
    __builtin_amdgcn_global_load_lds((const __attribute__((address_space(1))) u32*)g,
                                     (__attribute__((address_space(3))) u32*)l,
                                     16, 0, 0);
}

// ---------------------------------------------------------------------------
// feats NCHW fp32 -> zero-padded NHWC bf16  [B][52][39][512] (interior only)
// ---------------------------------------------------------------------------
__global__ __launch_bounds__(256) void pad_kernel(const float* __restrict__ feats,
                                                  u16* __restrict__ fpad) {
    __shared__ float t[64][65];
    const int b  = blockIdx.z;
    const int c0 = blockIdx.y * 64;
    const int p0 = blockIdx.x * 64;
    const int tid = threadIdx.x;
    {
        const int cl = tid >> 2, seg = tid & 3;
        const float* src = feats + ((size_t)b * NCH + c0 + cl) * PIX;
        const int pbase = p0 + seg * 16;
        #pragma unroll
        for (int i = 0; i < 16; i++) {
            int p = pbase + i;
            t[cl][seg * 16 + i] = (p < PIX) ? src[p] : 0.f;
        }
    }
    __syncthreads();
    {
        const int pl = tid >> 2, cs = tid & 3;
        const int p = p0 + pl;
        if (p < PIX) {
            const int h = p / FW, w = p % FW;
            size_t dst = (((size_t)b * HP + h + 1) * WP + (w + 1)) * NCH + c0 + cs * 16;
            u32 pk[8];
            #pragma unroll
            for (int i = 0; i < 8; i++) {
                u32 lo = f2bf(t[cs * 16 + 2 * i][pl]);
                u32 hi = f2bf(t[cs * 16 + 2 * i + 1][pl]);
                pk[i] = lo | (hi << 16);
            }
            *(uint4*)&fpad[dst]     = make_uint4(pk[0], pk[1], pk[2], pk[3]);
            *(uint4*)&fpad[dst + 8] = make_uint4(pk[4], pk[5], pk[6], pk[7]);
        }
    }
}

// zero only the 178 border pixels/batch instead of memsetting all 66 MB
__global__ __launch_bounds__(256) void border_kernel(u16* __restrict__ fpad) {
    int t = blockIdx.x * 256 + threadIdx.x;   // 32*178*64 = 364544 total
    int c8 = t & 63;
    int pi = (t >> 6) % 178;
    int b  = (t >> 6) / 178;
    int h, w;
    if (pi < 39)       { h = 0;        w = pi; }
    else if (pi < 78)  { h = 51;       w = pi - 39; }
    else if (pi < 128) { h = pi - 77;  w = 0; }
    else               { h = pi - 127; w = 38; }
    size_t dst = (((size_t)b * HP + h) * WP + w) * NCH + c8 * 8;
    *(uint4*)&fpad[dst] = make_uint4(0, 0, 0, 0);
}

// ---------------------------------------------------------------------------
// merged weight prep:
// W3 [co][ci][3][3] fp32 -> Wbt [co][k] bf16, k = (dy*3+dx)*512 + ci
// Wcls [18][512] + Wloc [36][512] fp32 -> Wcb [54][512] bf16
// ---------------------------------------------------------------------------
__global__ void wprep(const float* __restrict__ w3, const float* __restrict__ wcls,
                      const float* __restrict__ wloc,
                      u16* __restrict__ wbt, u16* __restrict__ wcb) {
    int t = blockIdx.x * 256 + threadIdx.x;
    if (t < W3N) {
        int co = t / KTOT, k = t % KTOT;
        int dydx = k >> 9, ci = k & 511;
        wbt[t] = f2bf(w3[((size_t)co * NCH + ci) * 9 + dydx]);
    } else {
        int t2 = t - W3N;
        if (t2 < 54 * 512) {
            int c = t2 >> 9, ci = t2 & 511;
            float v = (c < 18) ? wcls[c * 512 + ci] : wloc[(c - 18) * 512 + ci];
            wcb[t2] = f2bf(v);
        }
    }
}

// ---------------------------------------------------------------------------
// conv3x3 + bias + relu as implicit GEMM, bf16 MFMA 16x16x32.
// BK=64 (72 barrier-pairs instead of 144), global_load_lds width=16 into
// XOR-swizzled [128][64] tiles: phys_seg = seg ^ (row&7) folded into the
// staging lanes' GLOBAL addresses (padding is forbidden by the wave-uniform
// base + lane*16 LDS scatter; swizzling which data a lane fetches is not).
// Read side: quad q at row lm reads phys_seg ((kh<<2)|q)^(lm&7) -> every
// bank-group touched by exactly 2 lanes = conflict-free b128 floor.
// ---------------------------------------------------------------------------
__global__ __launch_bounds__(256) void conv3x3_mfma(const u16* __restrict__ fpad,
                                                    const u16* __restrict__ wbt,
                                                    const float* __restrict__ b3,
                                                    u16* __restrict__ conv1) {
    __shared__ __align__(16) u16 As[128][64];
    __shared__ __align__(16) u16 Bs[128][64];

    const int tid = threadIdx.x;
    const int m_base = blockIdx.x * 128;
    const int n_base = blockIdx.y * 128;
    const int wave = tid >> 6;
    const int lane = tid & 63;

    const int srow  = tid >> 3;                 // 0..31: row within a round
    const int seg_g = (tid & 7) ^ (srow & 7);   // swizzled 16B k-segment

    int rbA[4];
    #pragma unroll
    for (int r = 0; r < 4; r++) {
        int m = m_base + r * 32 + srow;
        int mm = (m < MTOT) ? m : 0;
        int b = mm / PIX, p = mm % PIX;
        int y = p / FW, x = p % FW;
        rbA[r] = ((b * HP + y) * WP + x) * NCH + seg_g * 8;
    }
    int rbB[4];
    #pragma unroll
    for (int r = 0; r < 4; r++) {
        int n = n_base + r * 32 + srow;
        rbB[r] = n * KTOT + seg_g * 8;
    }

    u16* const asb = &As[0][0] + wave * 512;    // round r adds r*2048 elems
    u16* const bsb = &Bs[0][0] + wave * 512;

    const int wm = (wave >> 1) * 64;
    const int wn = (wave & 1) * 64;
    const int lm = lane & 15;
    const int quad = lane >> 4;
    const int x7 = lm & 7;                      // == row&7 for all frag rows

    v4f acc[4][4];
    #pragma unroll
    for (int i = 0; i < 4; i++)
        #pragma unroll
        for (int j = 0; j < 4; j++)
            #pragma unroll
            for (int r = 0; r < 4; r++) acc[i][j][r] = 0.f;

    for (int k0 = 0; k0 < KTOT; k0 += 64) {
        const int dydx = k0 >> 9;
        const int ci0  = k0 & 511;
        const int offA = ((dydx / 3) * WP + (dydx % 3)) * NCH + ci0;
        #pragma unroll
        for (int r = 0; r < 4; r++)
            gl_lds16(fpad + rbA[r] + offA, asb + r * 2048);
        #pragma unroll
        for (int r = 0; r < 4; r++)
            gl_lds16(wbt + rbB[r] + k0, bsb + r * 2048);
        __syncthreads();

        #pragma unroll
        for (int kh = 0; kh < 2; kh++) {
            const int ps = (((kh << 2) | quad) ^ x7) * 8;   // phys elem offset
            v8bf af[4], bfv[4];
            #pragma unroll
            for (int i = 0; i < 4; i++)
                af[i]  = *(const v8bf*)(&As[0][0] + (wm + i * 16 + lm) * 64 + ps);
            #pragma unroll
            for (int i = 0; i < 4; i++)
                bfv[i] = *(const v8bf*)(&Bs[0][0] + (wn + i * 16 + lm) * 64 + ps);
            #pragma unroll
            for (int i = 0; i < 4; i++)
                #pragma unroll
                for (int j = 0; j < 4; j++)
                    acc[i][j] = __builtin_amdgcn_mfma_f32_16x16x32_bf16(af[i], bfv[j], acc[i][j], 0, 0, 0);
        }
        __syncthreads();
    }

    // epilogue: bias + relu, store bf16 conv1[m][n]
    #pragma unroll
    for (int j = 0; j < 4; j++) {
        const int n = n_base + wn + j * 16 + lm;
        const float bias = b3[n];
        #pragma unroll
        for (int i = 0; i < 4; i++) {
            #pragma unroll
            for (int r = 0; r < 4; r++) {
                int m = m_base + wm + i * 16 + quad * 4 + r;
                if (m < MTOT) {
                    float v = acc[i][j][r] + bias;
                    v = v > 0.f ? v : 0.f;
                    conv1[(size_t)m * NCH + n] = f2bf(v);
                }
            }
        }
    }
}

// ---------------------------------------------------------------------------
// head: cls (18) + loc (36) 1x1 convs over conv1, fused pairwise softmax.
// ---------------------------------------------------------------------------
__global__ __launch_bounds__(256) void head_kernel(const u16* __restrict__ conv1,
                                                   const u16* __restrict__ wcb,
                                                   const float* __restrict__ bcls,
                                                   const float* __restrict__ bloc,
                                                   float* __restrict__ out) {
    __shared__ __align__(16) u16 xl[4][520];
    __shared__ float cls_l[4][18];
    const int tid = threadIdx.x;
    const int m0 = blockIdx.x * 4;
    {
        const int r = tid & 3;
        const int kk = (tid >> 2) * 8;
        *(uint4*)&xl[r][kk] = *(const uint4*)&conv1[(size_t)(m0 + r) * NCH + kk];
    }
    __syncthreads();
    const int c = tid >> 2;
    const int pix = tid & 3;
    float a0 = 0.f, a1 = 0.f, a2 = 0.f, a3 = 0.f;
    if (c < 54) {
        const uint4* wp = (const uint4*)(wcb + c * 512);
        #pragma unroll 8
        for (int it = 0; it < 64; it++) {
            uint4 xv = *(const uint4*)&xl[pix][it * 8];
            uint4 wv = wp[it];
            a0 = fmaf(bf_lo(xv.x), bf_lo(wv.x), a0);
            a1 = fmaf(bf_hi(xv.x), bf_hi(wv.x), a1);
            a2 = fmaf(bf_lo(xv.y), bf_lo(wv.y), a2);
            a3 = fmaf(bf_hi(xv.y), bf_hi(wv.y), a3);
            a0 = fmaf(bf_lo(xv.z), bf_lo(wv.z), a0);
            a1 = fmaf(bf_hi(xv.z), bf_hi(wv.z), a1);
            a2 = fmaf(bf_lo(xv.w), bf_lo(wv.w), a2);
            a3 = fmaf(bf_hi(xv.w), bf_hi(wv.w), a3);
        }
    }
    float acc = (a0 + a1) + (a2 + a3);
    const int m = m0 + pix;
    const int b = m / PIX;
    const int p = m % PIX;
    if (c >= 18 && c < 54) {
        out[(size_t)PROB_N + ((size_t)b * 36 + (c - 18)) * PIX + p] = acc + bloc[c - 18];
    }
    if (c < 18) cls_l[pix][c] = acc + bcls[c];
    __syncthreads();
    if (c < 9) {
        float s0 = cls_l[pix][c], s1 = cls_l[pix][c + 9];
        float mx = fmaxf(s0, s1);
        float e0 = expf(s0 - mx), e1 = expf(s1 - mx);
        float inv = 1.f / (e0 + e1);
        out[((size_t)b * 18 + c) * PIX + p]     = e0 * inv;
        out[((size_t)b * 18 + c + 9) * PIX + p] = e1 * inv;
    }
}

// ---------------------------------------------------------------------------
// per-(b,a): max IoU over 20 GTs + argmax (first-max); per-(b,g) best anchor
// via u64 key (iou_bits<<32 | ~a) -> first-index tie-break, wave-reduced.
// ---------------------------------------------------------------------------
__global__ __launch_bounds__(256) void iou_kernel(const float* __restrict__ anchors,
                                                  const float* __restrict__ gtb,
                                                  int A,
                                                  float* __restrict__ max_iou,
                                                  int* __restrict__ matched,
                                                  u64* __restrict__ gtkey) {
    __shared__ float g[NG * 4];
    __shared__ u64 wk[4][NG];
    const int b = blockIdx.y;
    const int tid = threadIdx.x;
    if (tid < NG * 4) g[tid] = gtb[b * NG * 4 + tid];
    __syncthreads();
    const int a = blockIdx.x * 256 + tid;
    const bool act = a < A;
    const int aa = act ? a : 0;
    const float ax1 = anchors[aa * 4 + 0], ay1 = anchors[aa * 4 + 1];
    const float ax2 = anchors[aa * 4 + 2], ay2 = anchors[aa * 4 + 3];
    const float areaA = (ax2 - ax1) * (ay2 - ay1);
    float best = -1.f;
    int bg = 0;
    const int lane = tid & 63, wave = tid >> 6;
    for (int gi = 0; gi < NG; gi++) {
        float gx1 = g[gi * 4], gy1 = g[gi * 4 + 1], gx2 = g[gi * 4 + 2], gy2 = g[gi * 4 + 3];
        float iw = fmaxf(fminf(ax2, gx2) - fmaxf(ax1, gx1), 0.f);
        float ih = fmaxf(fminf(ay2, gy2) - fmaxf(ay1, gy1), 0.f);
        float inter = iw * ih;
        float areaG = (gx2 - gx1) * (gy2 - gy1);
        float iou = inter / fmaxf(areaA + areaG - inter, 1e-8f);
        if (act && iou > best) { best = iou; bg = gi; }
        u64 key = act ? (((u64)__float_as_uint(iou) << 32) | (u64)(0xFFFFFFFFu - (u32)a)) : 0ull;
        #pragma unroll
        for (int off = 32; off; off >>= 1) {
            u64 o = __shfl_xor(key, off);
            key = (o > key) ? o : key;
        }
        if (lane == 0) wk[wave][gi] = key;
    }
    if (act) {
        max_iou[(size_t)b * A + a] = best;
        matched[(size_t)b * A + a] = bg;
    }
    __syncthreads();
    if (tid < NG) {
        u64 k = wk[0][tid];
        k = (wk[1][tid] > k) ? wk[1][tid] : k;
        k = (wk[2][tid] > k) ? wk[2][tid] : k;
        k = (wk[3][tid] > k) ? wk[3][tid] : k;
        atomicMax(&gtkey[b * NG + tid], k);
    }
}

// ---------------------------------------------------------------------------
// losses: labels = (best-anchor-of-some-gt) | (max_iou > 0.7)
// ---------------------------------------------------------------------------
__global__ __launch_bounds__(256) void loss_kernel(const float* __restrict__ gtb,
                                                   const int* __restrict__ idxs,
                                                   const float* __restrict__ max_iou,
                                                   const int* __restrict__ matched,
                                                   const u64* __restrict__ gtkey,
                                                   int A,
                                                   float* out) {
    __shared__ float g[NG * 4];
    __shared__ int gbest[NG];
    __shared__ float red[8];
    const int b = blockIdx.y;
    const int tid = threadIdx.x;
    if (tid < NG * 4) g[tid] = gtb[b * NG * 4 + tid];
    if (tid < NG) {
        u64 k = gtkey[b * NG + tid];
        gbest[tid] = (int)(0xFFFFFFFFu - (u32)(k & 0xFFFFFFFFull));
    }
    __syncthreads();
    const int a = blockIdx.x * 256 + tid;
    float lc = 0.f, ll = 0.f;
    if (a < A) {
        float mi = max_iou[(size_t)b * A + a];
        int lbl = (mi > 0.7f) ? 1 : 0;
        if (!lbl) {
            #pragma unroll
            for (int gi = 0; gi < NG; gi++) lbl |= (gbest[gi] == a);
        }
        const int idx = idxs[a];
        const int cpr = idx / PIX;
        const int rem = idx % PIX;
        float p0 = out[((size_t)b * 18 + cpr) * PIX + rem];
        float p1 = out[((size_t)b * 18 + cpr + 9) * PIX + rem];
        float pl = lbl ? p1 : p0;
        lc = -logf(pl);
        if (lbl) {
            const int mg = matched[(size_t)b * A + a];
            const int hh = idx / 333;
            const int r2 = idx % 333;
            const int ww = r2 / 9;
            const int c4 = r2 % 9;
            const int pp = hh * FW + ww;
            #pragma unroll
            for (int t = 0; t < 4; t++) {
                float lv = out[(size_t)PROB_N + ((size_t)b * 36 + c4 * 4 + t) * PIX + pp];
                float d = lv - g[mg * 4 + t];
                float ad = fabsf(d);
                ll += (ad < 1.f) ? 0.5f * d * d : ad - 0.5f;
            }
        }
    }
    #pragma unroll
    for (int off = 32; off; off >>= 1) {
        lc += __shfl_xor(lc, off);
        ll += __shfl_xor(ll, off);
    }
    const int lane = tid & 63, wave = tid >> 6;
    if (lane == 0) { red[wave] = lc; red[4 + wave] = ll; }
    __syncthreads();
    if (tid == 0) {
        float slc = red[0] + red[1] + red[2] + red[3];
        float sll = red[4] + red[5] + red[6] + red[7];
        atomicAdd(&out[LC_IDX], slc * (1.f / (32.f * (float)A)));
        atomicAdd(&out[LL_IDX], sll * (1.f / 256.f));
    }
}

// ---------------------------------------------------------------------------
extern "C" void kernel_launch(void* const* d_in, const int* in_sizes, int n_in,
                              void* d_out, int out_size, void* d_ws, size_t ws_size,
                              hipStream_t stream) {
    const float* feats   = (const float*)d_in[0];
    const float* gtb     = (const float*)d_in[1];
    const float* anchors = (const float*)d_in[2];
    const float* W3      = (const float*)d_in[3];
    const float* b3      = (const float*)d_in[4];
    const float* Wcls    = (const float*)d_in[5];
    const float* bcls    = (const float*)d_in[6];
    const float* Wloc    = (const float*)d_in[7];
    const float* bloc    = (const float*)d_in[8];
    const int*   idxs    = (const int*)d_in[9];
    const int A = in_sizes[9];
    float* out = (float*)d_out;

    char* ws = (char*)d_ws;
    size_t off = 0;
    auto alloc = [&](size_t bytes) -> void* {
        void* p = ws + off;
        off = (off + bytes + 255) & ~(size_t)255;
        return p;
    };
    const size_t fpad_n = (size_t)NBATCH * HP * WP * NCH;     // 33,226,752
    u16* fpad   = (u16*)alloc(fpad_n * 2);
    u16* wbt    = (u16*)alloc((size_t)NCH * KTOT * 2);
    u16* wcb    = (u16*)alloc((size_t)54 * 512 * 2);
    u16* conv1  = (u16*)alloc((size_t)MTOT * NCH * 2);
    u64* gtkey  = (u64*)alloc((size_t)NBATCH * NG * 8);
    float* max_iou = (float*)alloc((size_t)NBATCH * A * 4);
    int*   matched = (int*)alloc((size_t)NBATCH * A * 4);

    hipMemsetAsync(gtkey, 0, (size_t)NBATCH * NG * 8, stream);
    hipMemsetAsync(out + LC_IDX, 0, 8, stream);

    border_kernel<<<1424, 256, 0, stream>>>(fpad);
    pad_kernel<<<dim3(29, 8, NBATCH), 256, 0, stream>>>(feats, fpad);
    wprep<<<(W3N + 54 * 512 + 255) / 256, 256, 0, stream>>>(W3, Wcls, Wloc, wbt, wcb);
    conv3x3_mfma<<<dim3(463, 4), 256, 0, stream>>>(fpad, wbt, b3, conv1);
    head_kernel<<<MTOT / 4, 256, 0, stream>>>(conv1, wcb, bcls, bloc, out);
    const int ablk = (A + 255) / 256;
    iou_kernel<<<dim3(ablk, NBATCH), 256, 0, stream>>>(anchors, gtb, A, max_iou, matched, gtkey);
    loss_kernel<<<dim3(ablk, NBATCH), 256, 0, stream>>>(gtb, idxs, max_iou, matched, gtkey, A, out);
}

// Round 4
// 846.287 us; speedup vs baseline: 1.1094x; 1.0473x over previous
//
#include <hip/hip_runtime.h>
#include <stdint.h>

typedef unsigned short u16;
typedef unsigned int   u32;
typedef unsigned long long u64;

typedef __bf16 v8bf __attribute__((ext_vector_type(8)));
typedef float  v4f  __attribute__((ext_vector_type(4)));

// ---- problem constants ----
#define NBATCH 32
#define NCH    512
#define FH     50
#define FW     37
#define PIX    1850        // 50*37
#define MTOT   59200       // 32*1850
#define KTOT   4608        // 512*9
#define HP     52          // padded H
#define WP     39          // padded W
#define NG     20
#define W3N    (NCH*KTOT)  // 2359296

#define PROB_N 1065600     // 32*18*1850
#define LOC_N  2131200     // 32*36*1850
#define LC_IDX 3196800
#define LL_IDX 3196801

__device__ __forceinline__ u16 f2bf(float f) {          // round-to-nearest-even
    u32 u = __float_as_uint(f);
    u += 0x7fffu + ((u >> 16) & 1u);
    return (u16)(u >> 16);
}
__device__ __forceinline__ float bf_lo(u32 u){ return __uint_as_float(u << 16); }
__device__ __forceinline__ float bf_hi(u32 u){ return __uint_as_float(u & 0xffff0000u); }

// async global->LDS, 16B per lane. LDS dst = wave-uniform base + lane*16 (m104).
__device__ __forceinline__ void gl_lds16(const u16* g, u16* l) {
    __builtin_amdgcn_global_load_lds((const __attribute__((address_space(1))) u32*)g,
                                     (__attribute__((address_space(3))) u32*)l,
                                     16, 0, 0);
}

// ---------------------------------------------------------------------------
// feats NCHW fp32 -> zero-padded NHWC bf16  [B][52][39][512] (interior only)
// ---------------------------------------------------------------------------
__global__ __launch_bounds__(256) void pad_kernel(const float* __restrict__ feats,
                                                  u16* __restrict__ fpad) {
    __shared__ float t[64][65];
    const int b  = blockIdx.z;
    const int c0 = blockIdx.y * 64;
    const int p0 = blockIdx.x * 64;
    const int tid = threadIdx.x;
    {
        const int cl = tid >> 2, seg = tid & 3;
        const float* src = feats + ((size_t)b * NCH + c0 + cl) * PIX;
        const int pbase = p0 + seg * 16;
        #pragma unroll
        for (int i = 0; i < 16; i++) {
            int p = pbase + i;
            t[cl][seg * 16 + i] = (p < PIX) ? src[p] : 0.f;
        }
    }
    __syncthreads();
    {
        const int pl = tid >> 2, cs = tid & 3;
        const int p = p0 + pl;
        if (p < PIX) {
            const int h = p / FW, w = p % FW;
            size_t dst = (((size_t)b * HP + h + 1) * WP + (w + 1)) * NCH + c0 + cs * 16;
            u32 pk[8];
            #pragma unroll
            for (int i = 0; i < 8; i++) {
                u32 lo = f2bf(t[cs * 16 + 2 * i][pl]);
                u32 hi = f2bf(t[cs * 16 + 2 * i + 1][pl]);
                pk[i] = lo | (hi << 16);
            }
            *(uint4*)&fpad[dst]     = make_uint4(pk[0], pk[1], pk[2], pk[3]);
            *(uint4*)&fpad[dst + 8] = make_uint4(pk[4], pk[5], pk[6], pk[7]);
        }
    }
}

// zero only the 178 border pixels/batch instead of memsetting all 66 MB
__global__ __launch_bounds__(256) void border_kernel(u16* __restrict__ fpad) {
    int t = blockIdx.x * 256 + threadIdx.x;   // 32*178*64 = 364544 total
    int c8 = t & 63;
    int pi = (t >> 6) % 178;
    int b  = (t >> 6) / 178;
    int h, w;
    if (pi < 39)       { h = 0;        w = pi; }
    else if (pi < 78)  { h = 51;       w = pi - 39; }
    else if (pi < 128) { h = pi - 77;  w = 0; }
    else               { h = pi - 127; w = 38; }
    size_t dst = (((size_t)b * HP + h) * WP + w) * NCH + c8 * 8;
    *(uint4*)&fpad[dst] = make_uint4(0, 0, 0, 0);
}

// ---------------------------------------------------------------------------
// merged weight prep:
// W3 [co][ci][3][3] fp32 -> Wbt [co][k] bf16, k = (dy*3+dx)*512 + ci
// Wcls [18][512] + Wloc [36][512] fp32 -> Wcb [54][512] bf16
// ---------------------------------------------------------------------------
__global__ void wprep(const float* __restrict__ w3, const float* __restrict__ wcls,
                      const float* __restrict__ wloc,
                      u16* __restrict__ wbt, u16* __restrict__ wcb) {
    int t = blockIdx.x * 256 + threadIdx.x;
    if (t < W3N) {
        int co = t / KTOT, k = t % KTOT;
        int dydx = k >> 9, ci = k & 511;
        wbt[t] = f2bf(w3[((size_t)co * NCH + ci) * 9 + dydx]);
    } else {
        int t2 = t - W3N;
        if (t2 < 54 * 512) {
            int c = t2 >> 9, ci = t2 & 511;
            float v = (c < 18) ? wcls[c * 512 + ci] : wloc[(c - 18) * 512 + ci];
            wcb[t2] = f2bf(v);
        }
    }
}

// ---------------------------------------------------------------------------
// conv3x3 + bias + relu as implicit GEMM, bf16 MFMA 16x16x32.
// BK=64, global_load_lds width=16 into XOR-swizzled [128][64] tiles
// (phys_seg = seg ^ (row&7) folded into the staging lanes' global addresses).
// XCD-aware block remap (XCD = linear_bid % 8, m09): each XCD gets a
// CONTIGUOUS 58-m-tile span, and the 4 n-blocks of one m-tile are adjacent
// in that XCD's issue order -> A-tile (234 KB unique) is served from that
// XCD's L2 instead of re-fetched from HBM 4x. FETCH was 1.08 GB/dispatch
// (= the entire 437 us at 2.75 TB/s); ideal is ~175 MB.
// ---------------------------------------------------------------------------
__global__ __launch_bounds__(256) void conv3x3_mfma(const u16* __restrict__ fpad,
                                                    const u16* __restrict__ wbt,
                                                    const float* __restrict__ b3,
                                                    u16* __restrict__ conv1) {
    __shared__ __align__(16) u16 As[128][64];
    __shared__ __align__(16) u16 Bs[128][64];

    const int lid = blockIdx.x;                 // 0..1855
    const int xcd = lid & 7;
    const int n_idx = (lid >> 3) & 3;
    const int m_idx = xcd * 58 + (lid >> 5);
    if (m_idx >= 463) return;                   // 4 pad blocks (whole-block exit)
    const int m_base = m_idx * 128;
    const int n_base = n_idx * 128;

    const int tid = threadIdx.x;
    const int wave = tid >> 6;
    const int lane = tid & 63;

    const int srow  = tid >> 3;                 // 0..31: row within a round
    const int seg_g = (tid & 7) ^ (srow & 7);   // swizzled 16B k-segment

    int rbA[4];
    #pragma unroll
    for (int r = 0; r < 4; r++) {
        int m = m_base + r * 32 + srow;
        int mm = (m < MTOT) ? m : 0;
        int b = mm / PIX, p = mm % PIX;
        int y = p / FW, x = p % FW;
        rbA[r] = ((b * HP + y) * WP + x) * NCH + seg_g * 8;
    }
    int rbB[4];
    #pragma unroll
    for (int r = 0; r < 4; r++) {
        int n = n_base + r * 32 + srow;
        rbB[r] = n * KTOT + seg_g * 8;
    }

    u16* const asb = &As[0][0] + wave * 512;    // round r adds r*2048 elems
    u16* const bsb = &Bs[0][0] + wave * 512;

    const int wm = (wave >> 1) * 64;
    const int wn = (wave & 1) * 64;
    const int lm = lane & 15;
    const int quad = lane >> 4;
    const int x7 = lm & 7;                      // == row&7 for all frag rows

    v4f acc[4][4];
    #pragma unroll
    for (int i = 0; i < 4; i++)
        #pragma unroll
        for (int j = 0; j < 4; j++)
            #pragma unroll
            for (int r = 0; r < 4; r++) acc[i][j][r] = 0.f;

    for (int k0 = 0; k0 < KTOT; k0 += 64) {
        const int dydx = k0 >> 9;
        const int ci0  = k0 & 511;
        const int offA = ((dydx / 3) * WP + (dydx % 3)) * NCH + ci0;
        #pragma unroll
        for (int r = 0; r < 4; r++)
            gl_lds16(fpad + rbA[r] + offA, asb + r * 2048);
        #pragma unroll
        for (int r = 0; r < 4; r++)
            gl_lds16(wbt + rbB[r] + k0, bsb + r * 2048);
        __syncthreads();

        #pragma unroll
        for (int kh = 0; kh < 2; kh++) {
            const int ps = (((kh << 2) | quad) ^ x7) * 8;   // phys elem offset
            v8bf af[4], bfv[4];
            #pragma unroll
            for (int i = 0; i < 4; i++)
                af[i]  = *(const v8bf*)(&As[0][0] + (wm + i * 16 + lm) * 64 + ps);
            #pragma unroll
            for (int i = 0; i < 4; i++)
                bfv[i] = *(const v8bf*)(&Bs[0][0] + (wn + i * 16 + lm) * 64 + ps);
            #pragma unroll
            for (int i = 0; i < 4; i++)
                #pragma unroll
                for (int j = 0; j < 4; j++)
                    acc[i][j] = __builtin_amdgcn_mfma_f32_16x16x32_bf16(af[i], bfv[j], acc[i][j], 0, 0, 0);
        }
        __syncthreads();
    }

    // epilogue: bias + relu, store bf16 conv1[m][n]
    #pragma unroll
    for (int j = 0; j < 4; j++) {
        const int n = n_base + wn + j * 16 + lm;
        const float bias = b3[n];
        #pragma unroll
        for (int i = 0; i < 4; i++) {
            #pragma unroll
            for (int r = 0; r < 4; r++) {
                int m = m_base + wm + i * 16 + quad * 4 + r;
                if (m < MTOT) {
                    float v = acc[i][j][r] + bias;
                    v = v > 0.f ? v : 0.f;
                    conv1[(size_t)m * NCH + n] = f2bf(v);
                }
            }
        }
    }
}

// ---------------------------------------------------------------------------
// head: cls (18) + loc (36) 1x1 convs over conv1, fused pairwise softmax.
// ---------------------------------------------------------------------------
__global__ __launch_bounds__(256) void head_kernel(const u16* __restrict__ conv1,
                                                   const u16* __restrict__ wcb,
                                                   const float* __restrict__ bcls,
                                                   const float* __restrict__ bloc,
                                                   float* __restrict__ out) {
    __shared__ __align__(16) u16 xl[4][520];
    __shared__ float cls_l[4][18];
    const int tid = threadIdx.x;
    const int m0 = blockIdx.x * 4;
    {
        const int r = tid & 3;
        const int kk = (tid >> 2) * 8;
        *(uint4*)&xl[r][kk] = *(const uint4*)&conv1[(size_t)(m0 + r) * NCH + kk];
    }
    __syncthreads();
    const int c = tid >> 2;
    const int pix = tid & 3;
    float a0 = 0.f, a1 = 0.f, a2 = 0.f, a3 = 0.f;
    if (c < 54) {
        const uint4* wp = (const uint4*)(wcb + c * 512);
        #pragma unroll 8
        for (int it = 0; it < 64; it++) {
            uint4 xv = *(const uint4*)&xl[pix][it * 8];
            uint4 wv = wp[it];
            a0 = fmaf(bf_lo(xv.x), bf_lo(wv.x), a0);
            a1 = fmaf(bf_hi(xv.x), bf_hi(wv.x), a1);
            a2 = fmaf(bf_lo(xv.y), bf_lo(wv.y), a2);
            a3 = fmaf(bf_hi(xv.y), bf_hi(wv.y), a3);
            a0 = fmaf(bf_lo(xv.z), bf_lo(wv.z), a0);
            a1 = fmaf(bf_hi(xv.z), bf_hi(wv.z), a1);
            a2 = fmaf(bf_lo(xv.w), bf_lo(wv.w), a2);
            a3 = fmaf(bf_hi(xv.w), bf_hi(wv.w), a3);
        }
    }
    float acc = (a0 + a1) + (a2 + a3);
    const int m = m0 + pix;
    const int b = m / PIX;
    const int p = m % PIX;
    if (c >= 18 && c < 54) {
        out[(size_t)PROB_N + ((size_t)b * 36 + (c - 18)) * PIX + p] = acc + bloc[c - 18];
    }
    if (c < 18) cls_l[pix][c] = acc + bcls[c];
    __syncthreads();
    if (c < 9) {
        float s0 = cls_l[pix][c], s1 = cls_l[pix][c + 9];
        float mx = fmaxf(s0, s1);
        float e0 = expf(s0 - mx), e1 = expf(s1 - mx);
        float inv = 1.f / (e0 + e1);
        out[((size_t)b * 18 + c) * PIX + p]     = e0 * inv;
        out[((size_t)b * 18 + c + 9) * PIX + p] = e1 * inv;
    }
}

// ---------------------------------------------------------------------------
// per-(b,a): max IoU over 20 GTs + argmax (first-max); per-(b,g) best anchor
// via u64 key (iou_bits<<32 | ~a) -> first-index tie-break, wave-reduced.
// ---------------------------------------------------------------------------
__global__ __launch_bounds__(256) void iou_kernel(const float* __restrict__ anchors,
                                                  const float* __restrict__ gtb,
                                                  int A,
                                                  float* __restrict__ max_iou,
                                                  int* __restrict__ matched,
                                                  u64* __restrict__ gtkey) {
    __shared__ float g[NG * 4];
    __shared__ u64 wk[4][NG];
    const int b = blockIdx.y;
    const int tid = threadIdx.x;
    if (tid < NG * 4) g[tid] = gtb[b * NG * 4 + tid];
    __syncthreads();
    const int a = blockIdx.x * 256 + tid;
    const bool act = a < A;
    const int aa = act ? a : 0;
    const float ax1 = anchors[aa * 4 + 0], ay1 = anchors[aa * 4 + 1];
    const float ax2 = anchors[aa * 4 + 2], ay2 = anchors[aa * 4 + 3];
    const float areaA = (ax2 - ax1) * (ay2 - ay1);
    float best = -1.f;
    int bg = 0;
    const int lane = tid & 63, wave = tid >> 6;
    for (int gi = 0; gi < NG; gi++) {
        float gx1 = g[gi * 4], gy1 = g[gi * 4 + 1], gx2 = g[gi * 4 + 2], gy2 = g[gi * 4 + 3];
        float iw = fmaxf(fminf(ax2, gx2) - fmaxf(ax1, gx1), 0.f);
        float ih = fmaxf(fminf(ay2, gy2) - fmaxf(ay1, gy1), 0.f);
        float inter = iw * ih;
        float areaG = (gx2 - gx1) * (gy2 - gy1);
        float iou = inter / fmaxf(areaA + areaG - inter, 1e-8f);
        if (act && iou > best) { best = iou; bg = gi; }
        u64 key = act ? (((u64)__float_as_uint(iou) << 32) | (u64)(0xFFFFFFFFu - (u32)a)) : 0ull;
        #pragma unroll
        for (int off = 32; off; off >>= 1) {
            u64 o = __shfl_xor(key, off);
            key = (o > key) ? o : key;
        }
        if (lane == 0) wk[wave][gi] = key;
    }
    if (act) {
        max_iou[(size_t)b * A + a] = best;
        matched[(size_t)b * A + a] = bg;
    }
    __syncthreads();
    if (tid < NG) {
        u64 k = wk[0][tid];
        k = (wk[1][tid] > k) ? wk[1][tid] : k;
        k = (wk[2][tid] > k) ? wk[2][tid] : k;
        k = (wk[3][tid] > k) ? wk[3][tid] : k;
        atomicMax(&gtkey[b * NG + tid], k);
    }
}

// ---------------------------------------------------------------------------
// losses: labels = (best-anchor-of-some-gt) | (max_iou > 0.7)
// ---------------------------------------------------------------------------
__global__ __launch_bounds__(256) void loss_kernel(const float* __restrict__ gtb,
                                                   const int* __restrict__ idxs,
                                                   const float* __restrict__ max_iou,
                                                   const int* __restrict__ matched,
                                                   const u64* __restrict__ gtkey,
                                                   int A,
                                                   float* out) {
    __shared__ float g[NG * 4];
    __shared__ int gbest[NG];
    __shared__ float red[8];
    const int b = blockIdx.y;
    const int tid = threadIdx.x;
    if (tid < NG * 4) g[tid] = gtb[b * NG * 4 + tid];
    if (tid < NG) {
        u64 k = gtkey[b * NG + tid];
        gbest[tid] = (int)(0xFFFFFFFFu - (u32)(k & 0xFFFFFFFFull));
    }
    __syncthreads();
    const int a = blockIdx.x * 256 + tid;
    float lc = 0.f, ll = 0.f;
    if (a < A) {
        float mi = max_iou[(size_t)b * A + a];
        int lbl = (mi > 0.7f) ? 1 : 0;
        if (!lbl) {
            #pragma unroll
            for (int gi = 0; gi < NG; gi++) lbl |= (gbest[gi] == a);
        }
        const int idx = idxs[a];
        const int cpr = idx / PIX;
        const int rem = idx % PIX;
        float p0 = out[((size_t)b * 18 + cpr) * PIX + rem];
        float p1 = out[((size_t)b * 18 + cpr + 9) * PIX + rem];
        float pl = lbl ? p1 : p0;
        lc = -logf(pl);
        if (lbl) {
            const int mg = matched[(size_t)b * A + a];
            const int hh = idx / 333;
            const int r2 = idx % 333;
            const int ww = r2 / 9;
            const int c4 = r2 % 9;
            const int pp = hh * FW + ww;
            #pragma unroll
            for (int t = 0; t < 4; t++) {
                float lv = out[(size_t)PROB_N + ((size_t)b * 36 + c4 * 4 + t) * PIX + pp];
                float d = lv - g[mg * 4 + t];
                float ad = fabsf(d);
                ll += (ad < 1.f) ? 0.5f * d * d : ad - 0.5f;
            }
        }
    }
    #pragma unroll
    for (int off = 32; off; off >>= 1) {
        lc += __shfl_xor(lc, off);
        ll += __shfl_xor(ll, off);
    }
    const int lane = tid & 63, wave = tid >> 6;
    if (lane == 0) { red[wave] = lc; red[4 + wave] = ll; }
    __syncthreads();
    if (tid == 0) {
        float slc = red[0] + red[1] + red[2] + red[3];
        float sll = red[4] + red[5] + red[6] + red[7];
        atomicAdd(&out[LC_IDX], slc * (1.f / (32.f * (float)A)));
        atomicAdd(&out[LL_IDX], sll * (1.f / 256.f));
    }
}

// ---------------------------------------------------------------------------
extern "C" void kernel_launch(void* const* d_in, const int* in_sizes, int n_in,
                              void* d_out, int out_size, void* d_ws, size_t ws_size,
                              hipStream_t stream) {
    const float* feats   = (const float*)d_in[0];
    const float* gtb     = (const float*)d_in[1];
    const float* anchors = (const float*)d_in[2];
    const float* W3      = (const float*)d_in[3];
    const float* b3      = (const float*)d_in[4];
    const float* Wcls    = (const float*)d_in[5];
    const float* bcls    = (const float*)d_in[6];
    const float* Wloc    = (const float*)d_in[7];
    const float* bloc    = (const float*)d_in[8];
    const int*   idxs    = (const int*)d_in[9];
    const int A = in_sizes[9];
    float* out = (float*)d_out;

    char* ws = (char*)d_ws;
    size_t off = 0;
    auto alloc = [&](size_t bytes) -> void* {
        void* p = ws + off;
        off = (off + bytes + 255) & ~(size_t)255;
        return p;
    };
    const size_t fpad_n = (size_t)NBATCH * HP * WP * NCH;     // 33,226,752
    u16* fpad   = (u16*)alloc(fpad_n * 2);
    u16* wbt    = (u16*)alloc((size_t)NCH * KTOT * 2);
    u16* wcb    = (u16*)alloc((size_t)54 * 512 * 2);
    u16* conv1  = (u16*)alloc((size_t)MTOT * NCH * 2);
    u64* gtkey  = (u64*)alloc((size_t)NBATCH * NG * 8);
    float* max_iou = (float*)alloc((size_t)NBATCH * A * 4);
    int*   matched = (int*)alloc((size_t)NBATCH * A * 4);

    hipMemsetAsync(gtkey, 0, (size_t)NBATCH * NG * 8, stream);
    hipMemsetAsync(out + LC_IDX, 0, 8, stream);

    border_kernel<<<1424, 256, 0, stream>>>(fpad);
    pad_kernel<<<dim3(29, 8, NBATCH), 256, 0, stream>>>(feats, fpad);
    wprep<<<(W3N + 54 * 512 + 255) / 256, 256, 0, stream>>>(W3, Wcls, Wloc, wbt, wcb);
    conv3x3_mfma<<<1856, 256, 0, stream>>>(fpad, wbt, b3, conv1);
    head_kernel<<<MTOT / 4, 256, 0, stream>>>(conv1, wcb, bcls, bloc, out);
    const int ablk = (A + 255) / 256;
    iou_kernel<<<dim3(ablk, NBATCH), 256, 0, stream>>>(anchors, gtb, A, max_iou, matched, gtkey);
    loss_kernel<<<dim3(ablk, NBATCH), 256, 0, stream>>>(gtb, idxs, max_iou, matched, gtkey, A, out);
}

// Round 6
// 789.077 us; speedup vs baseline: 1.1899x; 1.0725x over previous
//
#include <hip/hip_runtime.h>
#include <stdint.h>

typedef unsigned short u16;
typedef unsigned int   u32;
typedef unsigned long long u64;

typedef __bf16 v8bf __attribute__((ext_vector_type(8)));
typedef float  v4f  __attribute__((ext_vector_type(4)));

// ---- problem constants ----
#define NBATCH 32
#define NCH    512
#define FH     50
#define FW     37
#define PIX    1850        // 50*37
#define MTOT   59200       // 32*1850
#define KTOT   4608        // 512*9
#define HP     52          // padded H
#define WP     39          // padded W
#define NG     20
#define W3N    (NCH*KTOT)  // 2359296
#define WCBN   (64*512)    // padded head weights (rows 54..63 zero)
#define BORDN  364544      // 32*178*64 border uint4 writes

#define PROB_N 1065600     // 32*18*1850
#define LC_IDX 3196800
#define LL_IDX 3196801

__device__ __forceinline__ u16 f2bf(float f) {          // round-to-nearest-even
    u32 u = __float_as_uint(f);
    u += 0x7fffu + ((u >> 16) & 1u);
    return (u16)(u >> 16);
}

// async global->LDS, 16B per lane. LDS dst = wave-uniform base + lane*16 (m104).
__device__ __forceinline__ void gl_lds16(const u16* g, u16* l) {
    __builtin_amdgcn_global_load_lds((const __attribute__((address_space(1))) u32*)g,
                                     (__attribute__((address_space(3))) u32*)l,
                                     16, 0, 0);
}

// ---------------------------------------------------------------------------
// feats NCHW fp32 -> zero-padded NHWC bf16  [B][52][39][512] (interior only)
// ---------------------------------------------------------------------------
__global__ __launch_bounds__(256) void pad_kernel(const float* __restrict__ feats,
                                                  u16* __restrict__ fpad) {
    __shared__ float t[64][65];
    const int b  = blockIdx.z;
    const int c0 = blockIdx.y * 64;
    const int p0 = blockIdx.x * 64;
    const int tid = threadIdx.x;
    {
        const int cl = tid >> 2, seg = tid & 3;
        const float* src = feats + ((size_t)b * NCH + c0 + cl) * PIX;
        const int pbase = p0 + seg * 16;
        #pragma unroll
        for (int i = 0; i < 16; i++) {
            int p = pbase + i;
            t[cl][seg * 16 + i] = (p < PIX) ? src[p] : 0.f;
        }
    }
    __syncthreads();
    {
        const int pl = tid >> 2, cs = tid & 3;
        const int p = p0 + pl;
        if (p < PIX) {
            const int h = p / FW, w = p % FW;
            size_t dst = (((size_t)b * HP + h + 1) * WP + (w + 1)) * NCH + c0 + cs * 16;
            u32 pk[8];
            #pragma unroll
            for (int i = 0; i < 8; i++) {
                u32 lo = f2bf(t[cs * 16 + 2 * i][pl]);
                u32 hi = f2bf(t[cs * 16 + 2 * i + 1][pl]);
                pk[i] = lo | (hi << 16);
            }
            *(uint4*)&fpad[dst]     = make_uint4(pk[0], pk[1], pk[2], pk[3]);
            *(uint4*)&fpad[dst + 8] = make_uint4(pk[4], pk[5], pk[6], pk[7]);
        }
    }
}

// ---------------------------------------------------------------------------
// merged prep: W3 repack + head-weight repack (zero-padded to 64 rows) +
// fpad border zeroing + loss-scalar zeroing. One launch, no memsets.
// ---------------------------------------------------------------------------
__global__ void prep_kernel(const float* __restrict__ w3, const float* __restrict__ wcls,
                            const float* __restrict__ wloc,
                            u16* __restrict__ wbt, u16* __restrict__ wcb,
                            u16* __restrict__ fpad, float* __restrict__ out) {
    int t = blockIdx.x * 256 + threadIdx.x;
    if (t < 2) out[LC_IDX + t] = 0.f;
    if (t < W3N) {
        int co = t / KTOT, k = t % KTOT;
        int dydx = k >> 9, ci = k & 511;
        wbt[t] = f2bf(w3[((size_t)co * NCH + ci) * 9 + dydx]);
    } else if (t < W3N + WCBN) {
        int t2 = t - W3N;
        int c = t2 >> 9, ci = t2 & 511;
        float v = (c < 18) ? wcls[c * 512 + ci]
                : (c < 54) ? wloc[(c - 18) * 512 + ci] : 0.f;
        wcb[t2] = f2bf(v);
    } else if (t < W3N + WCBN + BORDN) {
        int t3 = t - (W3N + WCBN);
        int c8 = t3 & 63;
        int pi = (t3 >> 6) % 178;
        int b  = (t3 >> 6) / 178;
        int h, w;
        if (pi < 39)       { h = 0;        w = pi; }
        else if (pi < 78)  { h = 51;       w = pi - 39; }
        else if (pi < 128) { h = pi - 77;  w = 0; }
        else               { h = pi - 127; w = 38; }
        size_t dst = (((size_t)b * HP + h) * WP + w) * NCH + c8 * 8;
        *(uint4*)&fpad[dst] = make_uint4(0, 0, 0, 0);
    }
}

// ---------------------------------------------------------------------------
// conv3x3 + bias + relu as implicit GEMM, bf16 MFMA 16x16x32.  (UNCHANGED:
// BK=64, global_load_lds w=16, XOR-swizzled [128][64] tiles, XCD-aware
// remap -> FETCH at the ~175 MB ideal, 0 LDS conflicts.)
// ---------------------------------------------------------------------------
__global__ __launch_bounds__(256) void conv3x3_mfma(const u16* __restrict__ fpad,
                                                    const u16* __restrict__ wbt,
                                                    const float* __restrict__ b3,
                                                    u16* __restrict__ conv1) {
    __shared__ __align__(16) u16 As[128][64];
    __shared__ __align__(16) u16 Bs[128][64];

    const int lid = blockIdx.x;                 // 0..1855
    const int xcd = lid & 7;
    const int n_idx = (lid >> 3) & 3;
    const int m_idx = xcd * 58 + (lid >> 5);
    if (m_idx >= 463) return;                   // 4 pad blocks (whole-block exit)
    const int m_base = m_idx * 128;
    const int n_base = n_idx * 128;

    const int tid = threadIdx.x;
    const int wave = tid >> 6;
    const int lane = tid & 63;

    const int srow  = tid >> 3;                 // 0..31: row within a round
    const int seg_g = (tid & 7) ^ (srow & 7);   // swizzled 16B k-segment

    int rbA[4];
    #pragma unroll
    for (int r = 0; r < 4; r++) {
        int m = m_base + r * 32 + srow;
        int mm = (m < MTOT) ? m : 0;
        int b = mm / PIX, p = mm % PIX;
        int y = p / FW, x = p % FW;
        rbA[r] = ((b * HP + y) * WP + x) * NCH + seg_g * 8;
    }
    int rbB[4];
    #pragma unroll
    for (int r = 0; r < 4; r++) {
        int n = n_base + r * 32 + srow;
        rbB[r] = n * KTOT + seg_g * 8;
    }

    u16* const asb = &As[0][0] + wave * 512;    // round r adds r*2048 elems
    u16* const bsb = &Bs[0][0] + wave * 512;

    const int wm = (wave >> 1) * 64;
    const int wn = (wave & 1) * 64;
    const int lm = lane & 15;
    const int quad = lane >> 4;
    const int x7 = lm & 7;                      // == row&7 for all frag rows

    v4f acc[4][4];
    #pragma unroll
    for (int i = 0; i < 4; i++)
        #pragma unroll
        for (int j = 0; j < 4; j++)
            #pragma unroll
            for (int r = 0; r < 4; r++) acc[i][j][r] = 0.f;

    for (int k0 = 0; k0 < KTOT; k0 += 64) {
        const int dydx = k0 >> 9;
        const int ci0  = k0 & 511;
        const int offA = ((dydx / 3) * WP + (dydx % 3)) * NCH + ci0;
        #pragma unroll
        for (int r = 0; r < 4; r++)
            gl_lds16(fpad + rbA[r] + offA, asb + r * 2048);
        #pragma unroll
        for (int r = 0; r < 4; r++)
            gl_lds16(wbt + rbB[r] + k0, bsb + r * 2048);
        __syncthreads();

        #pragma unroll
        for (int kh = 0; kh < 2; kh++) {
            const int ps = (((kh << 2) | quad) ^ x7) * 8;   // phys elem offset
            v8bf af[4], bfv[4];
            #pragma unroll
            for (int i = 0; i < 4; i++)
                af[i]  = *(const v8bf*)(&As[0][0] + (wm + i * 16 + lm) * 64 + ps);
            #pragma unroll
            for (int i = 0; i < 4; i++)
                bfv[i] = *(const v8bf*)(&Bs[0][0] + (wn + i * 16 + lm) * 64 + ps);
            #pragma unroll
            for (int i = 0; i < 4; i++)
                #pragma unroll
                for (int j = 0; j < 4; j++)
                    acc[i][j] = __builtin_amdgcn_mfma_f32_16x16x32_bf16(af[i], bfv[j], acc[i][j], 0, 0, 0);
        }
        __syncthreads();
    }

    // epilogue: bias + relu, store bf16 conv1[m][n]
    #pragma unroll
    for (int j = 0; j < 4; j++) {
        const int n = n_base + wn + j * 16 + lm;
        const float bias = b3[n];
        #pragma unroll
        for (int i = 0; i < 4; i++) {
            #pragma unroll
            for (int r = 0; r < 4; r++) {
                int m = m_base + wm + i * 16 + quad * 4 + r;
                if (m < MTOT) {
                    float v = acc[i][j][r] + bias;
                    v = v > 0.f ? v : 0.f;
                    conv1[(size_t)m * NCH + n] = f2bf(v);
                }
            }
        }
    }
}

// ---------------------------------------------------------------------------
// head as MFMA GEMM: M=59200 (128/pixel-block), N=64 (54 used), K=512.
// FIX vs round 5: B slab is 64 rows x 8 KB/round -> must be staged by ALL
// 4 waves over 2 rounds (round r covers rows r*32+srow, LDS dest
// r*2048 + wave*512), not by 2 waves once (that left rows 16..63
// uninitialized -> NaN). Same XOR swizzle as A; read side unchanged.
// ---------------------------------------------------------------------------
__global__ __launch_bounds__(256) void head_mfma(const u16* __restrict__ conv1,
                                                 const u16* __restrict__ wcb,
                                                 const float* __restrict__ bcls,
                                                 const float* __restrict__ bloc,
                                                 float* __restrict__ out) {
    __shared__ __align__(16) u16 As[128][64];   // 16 KB: A slab (128 m x 64 k)
    __shared__ __align__(16) u16 Bs[64][64];    // 8 KB : B slab (64 n x 64 k)
    __shared__ float ct[128][66];               // 33.8 KB: fp32 C tile

    const int tid = threadIdx.x;
    const int m_base = blockIdx.x * 128;
    const int wave = tid >> 6;
    const int lane = tid & 63;
    const int srow  = tid >> 3;
    const int seg_g = (tid & 7) ^ (srow & 7);

    int rbA[4];
    #pragma unroll
    for (int r = 0; r < 4; r++) {
        int m = m_base + r * 32 + srow;
        int mm = (m < MTOT) ? m : 0;
        rbA[r] = mm * NCH + seg_g * 8;
    }
    int rbB[2];
    #pragma unroll
    for (int r = 0; r < 2; r++)
        rbB[r] = (r * 32 + srow) * NCH + seg_g * 8;

    u16* const asb = &As[0][0] + wave * 512;
    u16* const bsb = &Bs[0][0] + wave * 512;

    const int wn = wave * 16;
    const int lm = lane & 15;
    const int quad = lane >> 4;
    const int x7 = lm & 7;

    v4f acc[8];
    #pragma unroll
    for (int i = 0; i < 8; i++)
        #pragma unroll
        for (int r = 0; r < 4; r++) acc[i][r] = 0.f;

    for (int k0 = 0; k0 < NCH; k0 += 64) {
        #pragma unroll
        for (int r = 0; r < 4; r++)
            gl_lds16(conv1 + rbA[r] + k0, asb + r * 2048);
        #pragma unroll
        for (int r = 0; r < 2; r++)
            gl_lds16(wcb + rbB[r] + k0, bsb + r * 2048);
        __syncthreads();

        #pragma unroll
        for (int kh = 0; kh < 2; kh++) {
            const int ps = (((kh << 2) | quad) ^ x7) * 8;
            v8bf bf = *(const v8bf*)(&Bs[0][0] + (wn + lm) * 64 + ps);
            #pragma unroll
            for (int i = 0; i < 8; i++) {
                v8bf af = *(const v8bf*)(&As[0][0] + (i * 16 + lm) * 64 + ps);
                acc[i] = __builtin_amdgcn_mfma_f32_16x16x32_bf16(af, bf, acc[i], 0, 0, 0);
            }
        }
        __syncthreads();
    }

    // bias + park in fp32 LDS tile
    const int col = wn + lm;
    const float bias = (col < 18) ? bcls[col] : (col < 54) ? bloc[col - 18] : 0.f;
    #pragma unroll
    for (int i = 0; i < 8; i++)
        #pragma unroll
        for (int r = 0; r < 4; r++)
            ct[i * 16 + quad * 4 + r][col] = acc[i][r] + bias;
    __syncthreads();

    // softmax pairs + stores. c = tid>>2 (0..63), 4 pixel-lanes.
    const int c = tid >> 2;
    const int pix4 = tid & 3;
    for (int px = pix4; px < 128; px += 4) {
        const int m = m_base + px;
        if (m >= MTOT) break;
        const int b = m / PIX;
        const int p = m - b * PIX;
        if (c < 9) {
            float s0 = ct[px][c], s1 = ct[px][c + 9];
            float mx = fmaxf(s0, s1);
            float e0 = __expf(s0 - mx), e1 = __expf(s1 - mx);
            float inv = 1.f / (e0 + e1);
            out[((size_t)b * 18 + c) * PIX + p]     = e0 * inv;
            out[((size_t)b * 18 + c + 9) * PIX + p] = e1 * inv;
        } else if (c >= 18 && c < 54) {
            out[(size_t)PROB_N + ((size_t)b * 36 + (c - 18)) * PIX + p] = ct[px][c];
        }
    }
}

// ---------------------------------------------------------------------------
// fused IoU + losses: one block per batch. gt-best keys reduced in LDS
// (no global gtkey / max_iou / matched round-trips, no memsets).
// ---------------------------------------------------------------------------
__global__ __launch_bounds__(256) void iouloss_kernel(const float* __restrict__ anchors,
                                                      const float* __restrict__ gtb,
                                                      const int* __restrict__ idxs,
                                                      int A,
                                                      const float* __restrict__ outr,
                                                      float* __restrict__ out) {
    __shared__ float g[NG * 4];
    __shared__ u64 keys[NG];
    __shared__ int gbest[NG];
    __shared__ float red[8];
    const int b = blockIdx.y;
    const int tid = threadIdx.x;
    if (tid < NG * 4) g[tid] = gtb[b * NG * 4 + tid];
    if (tid < NG) keys[tid] = 0ull;
    __syncthreads();

    // pass 1: per-thread per-GT best key, then block max into LDS
    u64 lk[NG];
    #pragma unroll
    for (int gi = 0; gi < NG; gi++) lk[gi] = 0ull;
    for (int a = tid; a < A; a += 256) {
        const float ax1 = anchors[a * 4 + 0], ay1 = anchors[a * 4 + 1];
        const float ax2 = anchors[a * 4 + 2], ay2 = anchors[a * 4 + 3];
        const float areaA = (ax2 - ax1) * (ay2 - ay1);
        const u64 atag = (u64)(0xFFFFFFFFu - (u32)a);
        #pragma unroll
        for (int gi = 0; gi < NG; gi++) {
            float gx1 = g[gi*4], gy1 = g[gi*4+1], gx2 = g[gi*4+2], gy2 = g[gi*4+3];
            float iw = fmaxf(fminf(ax2, gx2) - fmaxf(ax1, gx1), 0.f);
            float ih = fmaxf(fminf(ay2, gy2) - fmaxf(ay1, gy1), 0.f);
            float inter = iw * ih;
            float areaG = (gx2 - gx1) * (gy2 - gy1);
            float iou = inter / fmaxf(areaA + areaG - inter, 1e-8f);
            u64 key = (((u64)__float_as_uint(iou)) << 32) | atag;
            if (key > lk[gi]) lk[gi] = key;
        }
    }
    #pragma unroll
    for (int gi = 0; gi < NG; gi++) {
        u64 k = lk[gi];
        #pragma unroll
        for (int off = 32; off; off >>= 1) {
            u64 o = __shfl_xor(k, off);
            k = (o > k) ? o : k;
        }
        if ((tid & 63) == 0) atomicMax(&keys[gi], k);
    }
    __syncthreads();
    if (tid < NG) gbest[tid] = (int)(0xFFFFFFFFu - (u32)(keys[tid] & 0xFFFFFFFFull));
    __syncthreads();

    // pass 2: labels + losses
    float lc = 0.f, ll = 0.f;
    for (int a = tid; a < A; a += 256) {
        const float ax1 = anchors[a * 4 + 0], ay1 = anchors[a * 4 + 1];
        const float ax2 = anchors[a * 4 + 2], ay2 = anchors[a * 4 + 3];
        const float areaA = (ax2 - ax1) * (ay2 - ay1);
        float best = -1.f;
        int bg = 0;
        #pragma unroll
        for (int gi = 0; gi < NG; gi++) {
            float gx1 = g[gi*4], gy1 = g[gi*4+1], gx2 = g[gi*4+2], gy2 = g[gi*4+3];
            float iw = fmaxf(fminf(ax2, gx2) - fmaxf(ax1, gx1), 0.f);
            float ih = fmaxf(fminf(ay2, gy2) - fmaxf(ay1, gy1), 0.f);
            float inter = iw * ih;
            float areaG = (gx2 - gx1) * (gy2 - gy1);
            float iou = inter / fmaxf(areaA + areaG - inter, 1e-8f);
            if (iou > best) { best = iou; bg = gi; }
        }
        int lbl = (best > 0.7f) ? 1 : 0;
        if (!lbl) {
            #pragma unroll
            for (int gi = 0; gi < NG; gi++) lbl |= (gbest[gi] == a);
        }
        const int idx = idxs[a];
        const int cpr = idx / PIX;
        const int rem = idx % PIX;
        float p0 = outr[((size_t)b * 18 + cpr) * PIX + rem];
        float p1 = outr[((size_t)b * 18 + cpr + 9) * PIX + rem];
        lc += -logf(lbl ? p1 : p0);
        if (lbl) {
            const int hh = idx / 333;
            const int r2 = idx % 333;
            const int ww = r2 / 9;
            const int c4 = r2 % 9;
            const int pp = hh * FW + ww;
            #pragma unroll
            for (int t = 0; t < 4; t++) {
                float lv = outr[(size_t)PROB_N + ((size_t)b * 36 + c4 * 4 + t) * PIX + pp];
                float d = lv - g[bg * 4 + t];
                float ad = fabsf(d);
                ll += (ad < 1.f) ? 0.5f * d * d : ad - 0.5f;
            }
        }
    }
    #pragma unroll
    for (int off = 32; off; off >>= 1) {
        lc += __shfl_xor(lc, off);
        ll += __shfl_xor(ll, off);
    }
    const int lane = tid & 63, wave = tid >> 6;
    if (lane == 0) { red[wave] = lc; red[4 + wave] = ll; }
    __syncthreads();
    if (tid == 0) {
        float slc = red[0] + red[1] + red[2] + red[3];
        float sll = red[4] + red[5] + red[6] + red[7];
        atomicAdd(&out[LC_IDX], slc * (1.f / (32.f * (float)A)));
        atomicAdd(&out[LL_IDX], sll * (1.f / 256.f));
    }
}

// ---------------------------------------------------------------------------
extern "C" void kernel_launch(void* const* d_in, const int* in_sizes, int n_in,
                              void* d_out, int out_size, void* d_ws, size_t ws_size,
                              hipStream_t stream) {
    const float* feats   = (const float*)d_in[0];
    const float* gtb     = (const float*)d_in[1];
    const float* anchors = (const float*)d_in[2];
    const float* W3      = (const float*)d_in[3];
    const float* b3      = (const float*)d_in[4];
    const float* Wcls    = (const float*)d_in[5];
    const float* bcls    = (const float*)d_in[6];
    const float* Wloc    = (const float*)d_in[7];
    const float* bloc    = (const float*)d_in[8];
    const int*   idxs    = (const int*)d_in[9];
    const int A = in_sizes[9];
    float* out = (float*)d_out;

    char* ws = (char*)d_ws;
    size_t off = 0;
    auto alloc = [&](size_t bytes) -> void* {
        void* p = ws + off;
        off = (off + bytes + 255) & ~(size_t)255;
        return p;
    };
    const size_t fpad_n = (size_t)NBATCH * HP * WP * NCH;     // 33,226,752
    u16* fpad   = (u16*)alloc(fpad_n * 2);
    u16* wbt    = (u16*)alloc((size_t)W3N * 2);
    u16* wcb    = (u16*)alloc((size_t)WCBN * 2);
    u16* conv1  = (u16*)alloc((size_t)MTOT * NCH * 2);

    const int prep_tot = W3N + WCBN + BORDN;
    prep_kernel<<<(prep_tot + 255) / 256, 256, 0, stream>>>(W3, Wcls, Wloc, wbt, wcb, fpad, out);
    pad_kernel<<<dim3(29, 8, NBATCH), 256, 0, stream>>>(feats, fpad);
    conv3x3_mfma<<<1856, 256, 0, stream>>>(fpad, wbt, b3, conv1);
    head_mfma<<<463, 256, 0, stream>>>(conv1, wcb, bcls, bloc, out);
    iouloss_kernel<<<dim3(1, NBATCH), 256, 0, stream>>>(anchors, gtb, idxs, A, out, out);
}

// Round 7
// 775.446 us; speedup vs baseline: 1.2108x; 1.0176x over previous
//
#include <hip/hip_runtime.h>
#include <stdint.h>

typedef unsigned short u16;
typedef unsigned int   u32;
typedef unsigned long long u64;

typedef __bf16 v8bf __attribute__((ext_vector_type(8)));
typedef float  v4f  __attribute__((ext_vector_type(4)));

// ---- problem constants ----
#define NBATCH 32
#define NCH    512
#define FH     50
#define FW     37
#define PIX    1850        // 50*37
#define MTOT   59200       // 32*1850
#define KTOT   4608        // 512*9
#define HP     52          // padded H
#define WP     39          // padded W
#define NG     20
#define W3N    (NCH*KTOT)  // 2359296
#define WCBN   (64*512)    // padded head weights (rows 54..63 zero)
#define BORDN  364544      // 32*178*64 border uint4 writes

#define PROB_N 1065600     // 32*18*1850
#define LC_IDX 3196800
#define LL_IDX 3196801

__device__ __forceinline__ u16 f2bf(float f) {          // round-to-nearest-even
    u32 u = __float_as_uint(f);
    u += 0x7fffu + ((u >> 16) & 1u);
    return (u16)(u >> 16);
}

// async global->LDS, 16B per lane. LDS dst = wave-uniform base + lane*16 (m104).
__device__ __forceinline__ void gl_lds16(const u16* g, u16* l) {
    __builtin_amdgcn_global_load_lds((const __attribute__((address_space(1))) u32*)g,
                                     (__attribute__((address_space(3))) u32*)l,
                                     16, 0, 0);
}

// ---------------------------------------------------------------------------
// feats NCHW fp32 -> zero-padded NHWC bf16  [B][52][39][512] (interior only)
// ---------------------------------------------------------------------------
__global__ __launch_bounds__(256) void pad_kernel(const float* __restrict__ feats,
                                                  u16* __restrict__ fpad) {
    __shared__ float t[64][65];
    const int b  = blockIdx.z;
    const int c0 = blockIdx.y * 64;
    const int p0 = blockIdx.x * 64;
    const int tid = threadIdx.x;
    {
        const int cl = tid >> 2, seg = tid & 3;
        const float* src = feats + ((size_t)b * NCH + c0 + cl) * PIX;
        const int pbase = p0 + seg * 16;
        #pragma unroll
        for (int i = 0; i < 16; i++) {
            int p = pbase + i;
            t[cl][seg * 16 + i] = (p < PIX) ? src[p] : 0.f;
        }
    }
    __syncthreads();
    {
        const int pl = tid >> 2, cs = tid & 3;
        const int p = p0 + pl;
        if (p < PIX) {
            const int h = p / FW, w = p % FW;
            size_t dst = (((size_t)b * HP + h + 1) * WP + (w + 1)) * NCH + c0 + cs * 16;
            u32 pk[8];
            #pragma unroll
            for (int i = 0; i < 8; i++) {
                u32 lo = f2bf(t[cs * 16 + 2 * i][pl]);
                u32 hi = f2bf(t[cs * 16 + 2 * i + 1][pl]);
                pk[i] = lo | (hi << 16);
            }
            *(uint4*)&fpad[dst]     = make_uint4(pk[0], pk[1], pk[2], pk[3]);
            *(uint4*)&fpad[dst + 8] = make_uint4(pk[4], pk[5], pk[6], pk[7]);
        }
    }
}

// ---------------------------------------------------------------------------
// merged prep: W3 repack + head-weight repack (zero-padded to 64 rows) +
// fpad border zeroing + loss-scalar zeroing. One launch, no memsets.
// ---------------------------------------------------------------------------
__global__ void prep_kernel(const float* __restrict__ w3, const float* __restrict__ wcls,
                            const float* __restrict__ wloc,
                            u16* __restrict__ wbt, u16* __restrict__ wcb,
                            u16* __restrict__ fpad, float* __restrict__ out) {
    int t = blockIdx.x * 256 + threadIdx.x;
    if (t < 2) out[LC_IDX + t] = 0.f;
    if (t < W3N) {
        int co = t / KTOT, k = t % KTOT;
        int dydx = k >> 9, ci = k & 511;
        wbt[t] = f2bf(w3[((size_t)co * NCH + ci) * 9 + dydx]);
    } else if (t < W3N + WCBN) {
        int t2 = t - W3N;
        int c = t2 >> 9, ci = t2 & 511;
        float v = (c < 18) ? wcls[c * 512 + ci]
                : (c < 54) ? wloc[(c - 18) * 512 + ci] : 0.f;
        wcb[t2] = f2bf(v);
    } else if (t < W3N + WCBN + BORDN) {
        int t3 = t - (W3N + WCBN);
        int c8 = t3 & 63;
        int pi = (t3 >> 6) % 178;
        int b  = (t3 >> 6) / 178;
        int h, w;
        if (pi < 39)       { h = 0;        w = pi; }
        else if (pi < 78)  { h = 51;       w = pi - 39; }
        else if (pi < 128) { h = pi - 77;  w = 0; }
        else               { h = pi - 127; w = 38; }
        size_t dst = (((size_t)b * HP + h) * WP + w) * NCH + c8 * 8;
        *(uint4*)&fpad[dst] = make_uint4(0, 0, 0, 0);
    }
}

// ---------------------------------------------------------------------------
// conv3x3 + bias + relu as implicit GEMM, bf16 MFMA 16x16x32.
// Round 7: BACK to BK=32 / 16 KB LDS (m97 structure) — BK=64's 32 KB halved
// occupancy (28.9%->20.6%, rounds 2/3) and that, not barrier count, was the
// binding constraint (BK=64 bought only 11 us). XCD remap kept (FETCH at the
// ~175 MB ideal). Swizzle NOTE: at 64 B row stride the bank index is
// 16*(row&1) + 4*seg', so seg^(row&3) would be 4-way conflicted; use
// seg ^ ((row>>1)&3) -> (parity,seg') takes 8 values x 2 lanes = conflict-free.
// ---------------------------------------------------------------------------
__global__ __launch_bounds__(256) void conv3x3_mfma(const u16* __restrict__ fpad,
                                                    const u16* __restrict__ wbt,
                                                    const float* __restrict__ b3,
                                                    u16* __restrict__ conv1) {
    __shared__ __align__(16) u16 As[128][32];   // 8 KB
    __shared__ __align__(16) u16 Bs[128][32];   // 8 KB

    const int lid = blockIdx.x;                 // 0..1855
    const int xcd = lid & 7;
    const int n_idx = (lid >> 3) & 3;
    const int m_idx = xcd * 58 + (lid >> 5);
    if (m_idx >= 463) return;                   // 4 pad blocks (whole-block exit)
    const int m_base = m_idx * 128;
    const int n_base = n_idx * 128;

    const int tid = threadIdx.x;
    const int wave = tid >> 6;
    const int lane = tid & 63;

    const int row   = tid >> 2;                 // 0..63: row within a round
    const int seg_g = (tid & 3) ^ ((tid >> 3) & 3);  // swizzled 16B k-segment

    int rbA[2];
    #pragma unroll
    for (int r = 0; r < 2; r++) {
        int m = m_base + r * 64 + row;
        int mm = (m < MTOT) ? m : 0;
        int b = mm / PIX, p = mm % PIX;
        int y = p / FW, x = p % FW;
        rbA[r] = ((b * HP + y) * WP + x) * NCH + seg_g * 8;
    }
    int rbB[2];
    #pragma unroll
    for (int r = 0; r < 2; r++) {
        int n = n_base + r * 64 + row;
        rbB[r] = n * KTOT + seg_g * 8;
    }

    u16* const asb = &As[0][0] + wave * 512;    // round r adds r*2048 elems
    u16* const bsb = &Bs[0][0] + wave * 512;

    const int wm = (wave >> 1) * 64;
    const int wn = (wave & 1) * 64;
    const int lm = lane & 15;
    const int quad = lane >> 4;
    const int ps = (quad ^ ((lm >> 1) & 3)) * 8;   // phys elem offset in row

    v4f acc[4][4];
    #pragma unroll
    for (int i = 0; i < 4; i++)
        #pragma unroll
        for (int j = 0; j < 4; j++)
            #pragma unroll
            for (int r = 0; r < 4; r++) acc[i][j][r] = 0.f;

    for (int k0 = 0; k0 < KTOT; k0 += 32) {
        const int dydx = k0 >> 9;
        const int ci0  = k0 & 511;
        const int offA = ((dydx / 3) * WP + (dydx % 3)) * NCH + ci0;
        #pragma unroll
        for (int r = 0; r < 2; r++)
            gl_lds16(fpad + rbA[r] + offA, asb + r * 2048);
        #pragma unroll
        for (int r = 0; r < 2; r++)
            gl_lds16(wbt + rbB[r] + k0, bsb + r * 2048);
        __syncthreads();

        v8bf af[4], bfv[4];
        #pragma unroll
        for (int i = 0; i < 4; i++)
            af[i]  = *(const v8bf*)(&As[0][0] + (wm + i * 16 + lm) * 32 + ps);
        #pragma unroll
        for (int i = 0; i < 4; i++)
            bfv[i] = *(const v8bf*)(&Bs[0][0] + (wn + i * 16 + lm) * 32 + ps);
        #pragma unroll
        for (int i = 0; i < 4; i++)
            #pragma unroll
            for (int j = 0; j < 4; j++)
                acc[i][j] = __builtin_amdgcn_mfma_f32_16x16x32_bf16(af[i], bfv[j], acc[i][j], 0, 0, 0);
        __syncthreads();
    }

    // epilogue: bias + relu, store bf16 conv1[m][n]
    #pragma unroll
    for (int j = 0; j < 4; j++) {
        const int n = n_base + wn + j * 16 + lm;
        const float bias = b3[n];
        #pragma unroll
        for (int i = 0; i < 4; i++) {
            #pragma unroll
            for (int r = 0; r < 4; r++) {
                int m = m_base + wm + i * 16 + quad * 4 + r;
                if (m < MTOT) {
                    float v = acc[i][j][r] + bias;
                    v = v > 0.f ? v : 0.f;
                    conv1[(size_t)m * NCH + n] = f2bf(v);
                }
            }
        }
    }
}

// ---------------------------------------------------------------------------
// head as MFMA GEMM: M=59200 (128/pixel-block), N=64 (54 used), K=512.
// (unchanged from round 6)
// ---------------------------------------------------------------------------
__global__ __launch_bounds__(256) void head_mfma(const u16* __restrict__ conv1,
                                                 const u16* __restrict__ wcb,
                                                 const float* __restrict__ bcls,
                                                 const float* __restrict__ bloc,
                                                 float* __restrict__ out) {
    __shared__ __align__(16) u16 As[128][64];   // 16 KB: A slab (128 m x 64 k)
    __shared__ __align__(16) u16 Bs[64][64];    // 8 KB : B slab (64 n x 64 k)
    __shared__ float ct[128][66];               // 33.8 KB: fp32 C tile

    const int tid = threadIdx.x;
    const int m_base = blockIdx.x * 128;
    const int wave = tid >> 6;
    const int lane = tid & 63;
    const int srow  = tid >> 3;
    const int seg_g = (tid & 7) ^ (srow & 7);

    int rbA[4];
    #pragma unroll
    for (int r = 0; r < 4; r++) {
        int m = m_base + r * 32 + srow;
        int mm = (m < MTOT) ? m : 0;
        rbA[r] = mm * NCH + seg_g * 8;
    }
    int rbB[2];
    #pragma unroll
    for (int r = 0; r < 2; r++)
        rbB[r] = (r * 32 + srow) * NCH + seg_g * 8;

    u16* const asb = &As[0][0] + wave * 512;
    u16* const bsb = &Bs[0][0] + wave * 512;

    const int wn = wave * 16;
    const int lm = lane & 15;
    const int quad = lane >> 4;
    const int x7 = lm & 7;

    v4f acc[8];
    #pragma unroll
    for (int i = 0; i < 8; i++)
        #pragma unroll
        for (int r = 0; r < 4; r++) acc[i][r] = 0.f;

    for (int k0 = 0; k0 < NCH; k0 += 64) {
        #pragma unroll
        for (int r = 0; r < 4; r++)
            gl_lds16(conv1 + rbA[r] + k0, asb + r * 2048);
        #pragma unroll
        for (int r = 0; r < 2; r++)
            gl_lds16(wcb + rbB[r] + k0, bsb + r * 2048);
        __syncthreads();

        #pragma unroll
        for (int kh = 0; kh < 2; kh++) {
            const int ps = (((kh << 2) | quad) ^ x7) * 8;
            v8bf bf = *(const v8bf*)(&Bs[0][0] + (wn + lm) * 64 + ps);
            #pragma unroll
            for (int i = 0; i < 8; i++) {
                v8bf af = *(const v8bf*)(&As[0][0] + (i * 16 + lm) * 64 + ps);
                acc[i] = __builtin_amdgcn_mfma_f32_16x16x32_bf16(af, bf, acc[i], 0, 0, 0);
            }
        }
        __syncthreads();
    }

    // bias + park in fp32 LDS tile
    const int col = wn + lm;
    const float bias = (col < 18) ? bcls[col] : (col < 54) ? bloc[col - 18] : 0.f;
    #pragma unroll
    for (int i = 0; i < 8; i++)
        #pragma unroll
        for (int r = 0; r < 4; r++)
            ct[i * 16 + quad * 4 + r][col] = acc[i][r] + bias;
    __syncthreads();

    // softmax pairs + stores. c = tid>>2 (0..63), 4 pixel-lanes.
    const int c = tid >> 2;
    const int pix4 = tid & 3;
    for (int px = pix4; px < 128; px += 4) {
        const int m = m_base + px;
        if (m >= MTOT) break;
        const int b = m / PIX;
        const int p = m - b * PIX;
        if (c < 9) {
            float s0 = ct[px][c], s1 = ct[px][c + 9];
            float mx = fmaxf(s0, s1);
            float e0 = __expf(s0 - mx), e1 = __expf(s1 - mx);
            float inv = 1.f / (e0 + e1);
            out[((size_t)b * 18 + c) * PIX + p]     = e0 * inv;
            out[((size_t)b * 18 + c + 9) * PIX + p] = e1 * inv;
        } else if (c >= 18 && c < 54) {
            out[(size_t)PROB_N + ((size_t)b * 36 + (c - 18)) * PIX + p] = ct[px][c];
        }
    }
}

// ---------------------------------------------------------------------------
// fused IoU + losses: one block per batch. gt-best keys reduced in LDS.
// (unchanged from round 6)
// ---------------------------------------------------------------------------
__global__ __launch_bounds__(256) void iouloss_kernel(const float* __restrict__ anchors,
                                                      const float* __restrict__ gtb,
                                                      const int* __restrict__ idxs,
                                                      int A,
                                                      const float* __restrict__ outr,
                                                      float* __restrict__ out) {
    __shared__ float g[NG * 4];
    __shared__ u64 keys[NG];
    __shared__ int gbest[NG];
    __shared__ float red[8];
    const int b = blockIdx.y;
    const int tid = threadIdx.x;
    if (tid < NG * 4) g[tid] = gtb[b * NG * 4 + tid];
    if (tid < NG) keys[tid] = 0ull;
    __syncthreads();

    // pass 1: per-thread per-GT best key, then block max into LDS
    u64 lk[NG];
    #pragma unroll
    for (int gi = 0; gi < NG; gi++) lk[gi] = 0ull;
    for (int a = tid; a < A; a += 256) {
        const float ax1 = anchors[a * 4 + 0], ay1 = anchors[a * 4 + 1];
        const float ax2 = anchors[a * 4 + 2], ay2 = anchors[a * 4 + 3];
        const float areaA = (ax2 - ax1) * (ay2 - ay1);
        const u64 atag = (u64)(0xFFFFFFFFu - (u32)a);
        #pragma unroll
        for (int gi = 0; gi < NG; gi++) {
            float gx1 = g[gi*4], gy1 = g[gi*4+1], gx2 = g[gi*4+2], gy2 = g[gi*4+3];
            float iw = fmaxf(fminf(ax2, gx2) - fmaxf(ax1, gx1), 0.f);
            float ih = fmaxf(fminf(ay2, gy2) - fmaxf(ay1, gy1), 0.f);
            float inter = iw * ih;
            float areaG = (gx2 - gx1) * (gy2 - gy1);
            float iou = inter / fmaxf(areaA + areaG - inter, 1e-8f);
            u64 key = (((u64)__float_as_uint(iou)) << 32) | atag;
            if (key > lk[gi]) lk[gi] = key;
        }
    }
    #pragma unroll
    for (int gi = 0; gi < NG; gi++) {
        u64 k = lk[gi];
        #pragma unroll
        for (int off = 32; off; off >>= 1) {
            u64 o = __shfl_xor(k, off);
            k = (o > k) ? o : k;
        }
        if ((tid & 63) == 0) atomicMax(&keys[gi], k);
    }
    __syncthreads();
    if (tid < NG) gbest[tid] = (int)(0xFFFFFFFFu - (u32)(keys[tid] & 0xFFFFFFFFull));
    __syncthreads();

    // pass 2: labels + losses
    float lc = 0.f, ll = 0.f;
    for (int a = tid; a < A; a += 256) {
        const float ax1 = anchors[a * 4 + 0], ay1 = anchors[a * 4 + 1];
        const float ax2 = anchors[a * 4 + 2], ay2 = anchors[a * 4 + 3];
        const float areaA = (ax2 - ax1) * (ay2 - ay1);
        float best = -1.f;
        int bg = 0;
        #pragma unroll
        for (int gi = 0; gi < NG; gi++) {
            float gx1 = g[gi*4], gy1 = g[gi*4+1], gx2 = g[gi*4+2], gy2 = g[gi*4+3];
            float iw = fmaxf(fminf(ax2, gx2) - fmaxf(ax1, gx1), 0.f);
            float ih = fmaxf(fminf(ay2, gy2) - fmaxf(ay1, gy1), 0.f);
            float inter = iw * ih;
            float areaG = (gx2 - gx1) * (gy2 - gy1);
            float iou = inter / fmaxf(areaA + areaG - inter, 1e-8f);
            if (iou > best) { best = iou; bg = gi; }
        }
        int lbl = (best > 0.7f) ? 1 : 0;
        if (!lbl) {
            #pragma unroll
            for (int gi = 0; gi < NG; gi++) lbl |= (gbest[gi] == a);
        }
        const int idx = idxs[a];
        const int cpr = idx / PIX;
        const int rem = idx % PIX;
        float p0 = outr[((size_t)b * 18 + cpr) * PIX + rem];
        float p1 = outr[((size_t)b * 18 + cpr + 9) * PIX + rem];
        lc += -logf(lbl ? p1 : p0);
        if (lbl) {
            const int hh = idx / 333;
            const int r2 = idx % 333;
            const int ww = r2 / 9;
            const int c4 = r2 % 9;
            const int pp = hh * FW + ww;
            #pragma unroll
            for (int t = 0; t < 4; t++) {
                float lv = outr[(size_t)PROB_N + ((size_t)b * 36 + c4 * 4 + t) * PIX + pp];
                float d = lv - g[bg * 4 + t];
                float ad = fabsf(d);
                ll += (ad < 1.f) ? 0.5f * d * d : ad - 0.5f;
            }
        }
    }
    #pragma unroll
    for (int off = 32; off; off >>= 1) {
        lc += __shfl_xor(lc, off);
        ll += __shfl_xor(ll, off);
    }
    const int lane = tid & 63, wave = tid >> 6;
    if (lane == 0) { red[wave] = lc; red[4 + wave] = ll; }
    __syncthreads();
    if (tid == 0) {
        float slc = red[0] + red[1] + red[2] + red[3];
        float sll = red[4] + red[5] + red[6] + red[7];
        atomicAdd(&out[LC_IDX], slc * (1.f / (32.f * (float)A)));
        atomicAdd(&out[LL_IDX], sll * (1.f / 256.f));
    }
}

// ---------------------------------------------------------------------------
extern "C" void kernel_launch(void* const* d_in, const int* in_sizes, int n_in,
                              void* d_out, int out_size, void* d_ws, size_t ws_size,
                              hipStream_t stream) {
    const float* feats   = (const float*)d_in[0];
    const float* gtb     = (const float*)d_in[1];
    const float* anchors = (const float*)d_in[2];
    const float* W3      = (const float*)d_in[3];
    const float* b3      = (const float*)d_in[4];
    const float* Wcls    = (const float*)d_in[5];
    const float* bcls    = (const float*)d_in[6];
    const float* Wloc    = (const float*)d_in[7];
    const float* bloc    = (const float*)d_in[8];
    const int*   idxs    = (const int*)d_in[9];
    const int A = in_sizes[9];
    float* out = (float*)d_out;

    char* ws = (char*)d_ws;
    size_t off = 0;
    auto alloc = [&](size_t bytes) -> void* {
        void* p = ws + off;
        off = (off + bytes + 255) & ~(size_t)255;
        return p;
    };
    const size_t fpad_n = (size_t)NBATCH * HP * WP * NCH;     // 33,226,752
    u16* fpad   = (u16*)alloc(fpad_n * 2);
    u16* wbt    = (u16*)alloc((size_t)W3N * 2);
    u16* wcb    = (u16*)alloc((size_t)WCBN * 2);
    u16* conv1  = (u16*)alloc((size_t)MTOT * NCH * 2);

    const int prep_tot = W3N + WCBN + BORDN;
    prep_kernel<<<(prep_tot + 255) / 256, 256, 0, stream>>>(W3, Wcls, Wloc, wbt, wcb, fpad, out);
    pad_kernel<<<dim3(29, 8, NBATCH), 256, 0, stream>>>(feats, fpad);
    conv3x3_mfma<<<1856, 256, 0, stream>>>(fpad, wbt, b3, conv1);
    head_mfma<<<463, 256, 0, stream>>>(conv1, wcb, bcls, bloc, out);
    iouloss_kernel<<<dim3(1, NBATCH), 256, 0, stream>>>(anchors, gtb, idxs, A, out, out);
}